// Round 1
// baseline (5541.458 us; speedup 1.0000x reference)
//
#include <hip/hip_runtime.h>
#include <hip/hip_bf16.h>

// Problem constants (fixed by setup_inputs)
constexpr int    TOT = 65536;       // nodes per side
constexpr int    Bg  = 128;         // graphs per side
constexpr int    FIN = 128;
constexpr int    F3c = 32;
constexpr long long Ec = 16LL * TOT; // 1048576 edges per side

// ---------------- small utility kernels ----------------
__global__ void fill1_k(float* __restrict__ p, int n) {
    int t = blockIdx.x * 256 + threadIdx.x;
    if (t < n) p[t] = 1.0f;
}

__global__ void degcnt_k(float* __restrict__ deg, const int* __restrict__ dst) {
    int t = blockIdx.x * 256 + threadIdx.x;
    atomicAdd(&deg[dst[t]], 1.0f);
}

__global__ void rsqrt_k(float* __restrict__ p, int n) {
    int t = blockIdx.x * 256 + threadIdx.x;
    if (t < n) p[t] = rsqrtf(p[t]);
}

__global__ void bcount_k(int* __restrict__ cnt, const int* __restrict__ batch) {
    int t = blockIdx.x * 256 + threadIdx.x;
    atomicAdd(&cnt[batch[t]], 1);
}

__global__ void scan_k(const int* __restrict__ cnt, int* __restrict__ st) {
    // two sides, serial 128-scan each (trivial)
    if (threadIdx.x < 2) {
        int o = 0;
        for (int q = 0; q < 128; ++q) { st[threadIdx.x * 128 + q] = o; o += cnt[threadIdx.x * 128 + q]; }
    }
}

// ---------------- GEMM: out[M,NC] = (relu?)X[M,K] @ W[K,NC] ----------------
// Thread-per-row, W staged in LDS, uniform ds_read_b128 broadcast of W rows.
template<int K, int NC, bool RELU>
__global__ __launch_bounds__(256) void gemm_k(const float* __restrict__ X,
                                              const float* __restrict__ W,
                                              float* __restrict__ out) {
    __shared__ float Ws[K * NC];
    const int tid = threadIdx.x;
    constexpr int WE4 = K * NC / 1024;  // float4 loads per thread
    {
        const float4* Wg = (const float4*)W;
        float4* Wp = (float4*)Ws;
#pragma unroll
        for (int it = 0; it < WE4; ++it) Wp[tid + it * 256] = Wg[tid + it * 256];
    }
    __syncthreads();
    const size_t row = (size_t)blockIdx.x * 256 + tid;
    const float4* Xr = (const float4*)(X + row * K);
    float acc[NC];
#pragma unroll
    for (int j = 0; j < NC; ++j) acc[j] = 0.f;
#pragma unroll 2
    for (int k4 = 0; k4 < K / 4; ++k4) {
        float4 xv = Xr[k4];
        if (RELU) {
            xv.x = fmaxf(xv.x, 0.f); xv.y = fmaxf(xv.y, 0.f);
            xv.z = fmaxf(xv.z, 0.f); xv.w = fmaxf(xv.w, 0.f);
        }
        const float xs[4] = {xv.x, xv.y, xv.z, xv.w};
#pragma unroll
        for (int kk = 0; kk < 4; ++kk) {
#pragma unroll
            for (int j4 = 0; j4 < NC / 4; ++j4) {
                float4 wv = *(const float4*)&Ws[(k4 * 4 + kk) * NC + j4 * 4];
                acc[j4 * 4 + 0] += xs[kk] * wv.x;
                acc[j4 * 4 + 1] += xs[kk] * wv.y;
                acc[j4 * 4 + 2] += xs[kk] * wv.z;
                acc[j4 * 4 + 3] += xs[kk] * wv.w;
            }
        }
    }
    float4* Or = (float4*)(out + row * NC);
#pragma unroll
    for (int j4 = 0; j4 < NC / 4; ++j4)
        Or[j4] = make_float4(acc[j4 * 4], acc[j4 * 4 + 1], acc[j4 * 4 + 2], acc[j4 * 4 + 3]);
}

// ---------------- GCN aggregation ----------------
// out = h * dis^2 + bias  (self-loop term, GEMM output h has no bias)
template<int NC>
__global__ __launch_bounds__(256) void initagg_k(float* __restrict__ out, const float* __restrict__ h,
                                                 const float* __restrict__ dis, const float* __restrict__ bias) {
    size_t t = (size_t)blockIdx.x * 256 + threadIdx.x;
    constexpr int PR = NC / 4;
    size_t i = t / PR; int c4 = (int)(t % PR) * 4;
    float dv = dis[i]; float inv = dv * dv;
    float4 hv = *(const float4*)&h[i * NC + c4];
    float4 o;
    o.x = hv.x * inv + bias[c4 + 0];
    o.y = hv.y * inv + bias[c4 + 1];
    o.z = hv.z * inv + bias[c4 + 2];
    o.w = hv.w * inv + bias[c4 + 3];
    *(float4*)&out[i * NC + c4] = o;
}

// out[dst] += h[src] * dis[src]*dis[dst], float4 atomics
template<int NC>
__global__ __launch_bounds__(256) void scatter_k(float* __restrict__ out, const float* __restrict__ h,
                                                 const float* __restrict__ dis,
                                                 const int* __restrict__ src, const int* __restrict__ dst) {
    size_t t = (size_t)blockIdx.x * 256 + threadIdx.x;
    constexpr int PR = NC / 4;
    size_t e = t / PR; int c4 = (int)(t % PR) * 4;
    int s = src[e], d = dst[e];
    float cf = dis[s] * dis[d];
    const float4 hv = *(const float4*)&h[(size_t)s * NC + c4];
    float* op = &out[(size_t)d * NC + c4];
    atomicAdd(op + 0, hv.x * cf);
    atomicAdd(op + 1, hv.y * cf);
    atomicAdd(op + 2, hv.z * cf);
    atomicAdd(op + 3, hv.w * cf);
}

// ---------------- attention pooling (one block per (side,graph)) ----------------
__global__ __launch_bounds__(256) void attpool_k(const float* __restrict__ af,
                                                 const int* __restrict__ cnt, const int* __restrict__ st,
                                                 const float* __restrict__ attW, float* __restrict__ pool) {
    const int side = blockIdx.x >> 7, b = blockIdx.x & 127;
    const float* h = af + (size_t)side * TOT * F3c;
    const int c = cnt[side * 128 + b], s0 = st[side * 128 + b];
    const int f = threadIdx.x & 31, grp = threadIdx.x >> 5;
    __shared__ float red[8][32];
    __shared__ float mhS[32], tS[32];
    float acc = 0.f;
    for (int i = grp; i < c; i += 8) acc += h[(size_t)(s0 + i) * F3c + f];
    red[grp][f] = acc;
    __syncthreads();
    if (threadIdx.x < 32) { float tt = 0; for (int g = 0; g < 8; ++g) tt += red[g][f]; mhS[f] = tt / (float)c; }
    __syncthreads();
    if (threadIdx.x < 32) {
        float g = 0;
        for (int k = 0; k < 32; ++k) g += mhS[k] * attW[k * 32 + f];
        tS[f] = tanhf(g);
    }
    __syncthreads();
    const float tf = tS[f];
    acc = 0.f;
    for (int i = grp; i < c; i += 8) {
        float hv = h[(size_t)(s0 + i) * F3c + f];
        float pr = hv * tf;
#pragma unroll
        for (int m = 16; m; m >>= 1) pr += __shfl_xor(pr, m, 32);
        float sA = 1.f / (1.f + expf(-pr));
        acc += hv * sA;
    }
    __syncthreads();
    red[grp][f] = acc;
    __syncthreads();
    if (threadIdx.x < 32) {
        float tt = 0; for (int g = 0; g < 8; ++g) tt += red[g][f];
        pool[(size_t)(side * 128 + b) * 32 + f] = tt;
    }
}

// ---------------- histogram (one block per graph pair) ----------------
// Pass 0: min/max of raw dots (sigmoid monotonic). Pass 1: bin sigmoid(dot).
__global__ __launch_bounds__(256) void hist_k(const float* __restrict__ af1,
                                              const float* __restrict__ af2,
                                              const int* __restrict__ cnt, const int* __restrict__ st,
                                              float* __restrict__ hist) {
    const int b = blockIdx.x;
    const int c1 = cnt[b], c2 = cnt[128 + b];
    const int s1 = st[b], s2 = st[128 + b];
    const int nn = max(c1, c2);
    __shared__ float D2[256 * 32];      // 32 KB j-half tile
    __shared__ int   hloc[256 * 17];    // private per-thread hists, stride-17 pad
    __shared__ float redn[256], redx[256];
    __shared__ float sMn, sRng;
    const int tid = threadIdx.x;
#pragma unroll
    for (int q = 0; q < 17; ++q) hloc[tid * 17 + q] = 0;
    float lmn = 1e30f, lmx = -1e30f;
    float vMn = 0.f, vRng = 1.f;
    for (int pass = 0; pass < 2; ++pass) {
        for (int jh = 0; jh < 2; ++jh) {
            __syncthreads();
            for (int e = tid; e < 256 * 8; e += 256) {   // stage D2 half-tile
                int j = e >> 3, q4 = (e & 7) * 4;
                int jg = jh * 256 + j;
                float4 v = make_float4(0.f, 0.f, 0.f, 0.f);
                if (jg < c2) v = *(const float4*)&af2[((size_t)(s2 + jg)) * 32 + q4];
                *(float4*)&D2[j * 32 + q4] = v;
            }
            __syncthreads();
            int jcnt = nn - jh * 256; jcnt = jcnt < 0 ? 0 : (jcnt > 256 ? 256 : jcnt);
            for (int ih = 0; ih < 2; ++ih) {
                const int i = ih * 256 + tid;
                if (i >= nn) continue;
                float r[32];
                if (i < c1) {
                    const float4* rp = (const float4*)&af1[((size_t)(s1 + i)) * 32];
#pragma unroll
                    for (int q = 0; q < 8; ++q) {
                        float4 v = rp[q];
                        r[q * 4] = v.x; r[q * 4 + 1] = v.y; r[q * 4 + 2] = v.z; r[q * 4 + 3] = v.w;
                    }
                } else {
#pragma unroll
                    for (int q = 0; q < 32; ++q) r[q] = 0.f;
                }
                for (int j = 0; j < jcnt; ++j) {
                    float d = 0.f;
#pragma unroll
                    for (int k = 0; k < 32; ++k) d += r[k] * D2[j * 32 + k];
                    if (pass == 0) { lmn = fminf(lmn, d); lmx = fmaxf(lmx, d); }
                    else {
                        float v = 1.f / (1.f + expf(-d));
                        float qq = (v - vMn) / vRng * 16.f;
                        int bi = (int)floorf(qq);
                        bi = bi < 0 ? 0 : (bi > 15 ? 15 : bi);
                        hloc[tid * 17 + bi] += 1;
                    }
                }
            }
        }
        if (pass == 0) {
            redn[tid] = lmn; redx[tid] = lmx;
            __syncthreads();
            for (int sr = 128; sr; sr >>= 1) {
                if (tid < sr) {
                    redn[tid] = fminf(redn[tid], redn[tid + sr]);
                    redx[tid] = fmaxf(redx[tid], redx[tid + sr]);
                }
                __syncthreads();
            }
            if (tid == 0) {
                float a = 1.f / (1.f + expf(-redn[0]));
                float bb = 1.f / (1.f + expf(-redx[0]));
                sMn = a; sRng = (bb > a) ? (bb - a) : 1.f;
            }
            __syncthreads();
            vMn = sMn; vRng = sRng;
        }
    }
    __syncthreads();
    __shared__ float binf[16];
    if (tid < 16) {
        int ssum = 0;
        for (int t2 = 0; t2 < 256; ++t2) ssum += hloc[t2 * 17 + tid];
        binf[tid] = (float)ssum;
    }
    __syncthreads();
    if (tid < 16) {
        float tot = 0; for (int q = 0; q < 16; ++q) tot += binf[q];
        hist[(size_t)b * 16 + tid] = binf[tid] / tot;
    }
}

// ---------------- NTN + final MLP (one block per graph) ----------------
__global__ __launch_bounds__(64) void final_k(const float* __restrict__ pool, const float* __restrict__ hist,
                                              const float* __restrict__ ntnW, const float* __restrict__ ntnV,
                                              const float* __restrict__ ntnb, const float* __restrict__ fc1W,
                                              const float* __restrict__ fc1b, const float* __restrict__ scW,
                                              const float* __restrict__ scb, float* __restrict__ out) {
    const int b = blockIdx.x;
    const int tid = threadIdx.x;
    __shared__ float P1[32], P2[32], feat[32], red[64];
    if (tid < 32) { P1[tid] = pool[b * 32 + tid]; P2[tid] = pool[4096 + b * 32 + tid]; }
    __syncthreads();
    const int k = tid & 15, part = tid >> 4;   // 4 parts over i (8 rows each)
    float acc = 0.f;
    for (int i = part * 8; i < part * 8 + 8; ++i) {
        float p1i = P1[i];
        for (int j = 0; j < 32; ++j) acc += p1i * P2[j] * ntnW[(i * 32 + j) * 16 + k];
    }
    red[tid] = acc;
    __syncthreads();
    if (tid < 16) {
        float bl = red[tid] + red[16 + tid] + red[32 + tid] + red[48 + tid];
        float blk = ntnb[tid];
        for (int i = 0; i < 32; ++i) blk += P1[i] * ntnV[tid * 64 + i];
        for (int j = 0; j < 32; ++j) blk += P2[j] * ntnV[tid * 64 + 32 + j];
        feat[tid] = fmaxf(bl + blk, 0.f);
        feat[16 + tid] = hist[b * 16 + tid];
    }
    __syncthreads();
    if (tid < 16) {
        float h = fc1b[tid];
        for (int f = 0; f < 32; ++f) h += feat[f] * fc1W[f * 16 + tid];
        red[tid] = fmaxf(h, 0.f);
    }
    __syncthreads();
    if (tid == 0) {
        float o = scb[0];
        for (int j = 0; j < 16; ++j) o += red[j] * scW[j];
        out[b] = 1.f / (1.f + expf(-o));
    }
}

// ---------------- launch ----------------
extern "C" void kernel_launch(void* const* d_in, const int* in_sizes, int n_in,
                              void* d_out, int out_size, void* d_ws, size_t ws_size,
                              hipStream_t stream) {
    const float* x1   = (const float*)d_in[0];
    const float* x2   = (const float*)d_in[1];
    const int*   ei1  = (const int*)d_in[2];
    const int*   ei2  = (const int*)d_in[3];
    const int*   bat1 = (const int*)d_in[4];
    const int*   bat2 = (const int*)d_in[5];
    const float* W1   = (const float*)d_in[6];
    const float* b1   = (const float*)d_in[7];
    const float* W2   = (const float*)d_in[8];
    const float* b2   = (const float*)d_in[9];
    const float* W3   = (const float*)d_in[10];
    const float* b3   = (const float*)d_in[11];
    const float* attW = (const float*)d_in[12];
    const float* ntnW = (const float*)d_in[13];
    const float* ntnV = (const float*)d_in[14];
    const float* ntnb = (const float*)d_in[15];
    const float* fc1W = (const float*)d_in[16];
    const float* fc1b = (const float*)d_in[17];
    const float* scW  = (const float*)d_in[18];
    const float* scb  = (const float*)d_in[19];
    float* out = (float*)d_out;

    // workspace layout (~67.7 MB)
    float* Hbuf = (float*)d_ws;                     // 131072*64 f32
    float* Gbuf = Hbuf + (size_t)131072 * 64;       // 131072*64 f32
    float* dis  = Gbuf + (size_t)131072 * 64;       // 131072 f32 (deg -> rsqrt)
    int*   cnt  = (int*)(dis + 131072);             // 256 int
    int*   st   = cnt + 256;                        // 256 int
    float* pool = (float*)(st + 256);               // 2*128*32 f32
    float* hist = pool + 8192;                      // 128*16 f32

    const int Eb = (int)(Ec / 256);                 // 4096 blocks over edges

    hipMemsetAsync(cnt, 0, 256 * sizeof(int), stream);
    fill1_k<<<512, 256, 0, stream>>>(dis, 131072);
    degcnt_k<<<Eb, 256, 0, stream>>>(dis,       ei1 + Ec);   // dst = ei[1]
    degcnt_k<<<Eb, 256, 0, stream>>>(dis + TOT, ei2 + Ec);
    bcount_k<<<256, 256, 0, stream>>>(cnt,       bat1);
    bcount_k<<<256, 256, 0, stream>>>(cnt + 128, bat2);
    rsqrt_k<<<512, 256, 0, stream>>>(dis, 131072);
    scan_k<<<1, 64, 0, stream>>>(cnt, st);

    // Layer 1 (K=128 -> 64), relu fused into next GEMM's load
    gemm_k<128, 64, false><<<256, 256, 0, stream>>>(x1, W1, Hbuf);
    gemm_k<128, 64, false><<<256, 256, 0, stream>>>(x2, W1, Hbuf + (size_t)TOT * 64);
    initagg_k<64><<<8192, 256, 0, stream>>>(Gbuf, Hbuf, dis, b1);
    scatter_k<64><<<65536, 256, 0, stream>>>(Gbuf, Hbuf, dis, ei1, ei1 + Ec);
    scatter_k<64><<<65536, 256, 0, stream>>>(Gbuf + (size_t)TOT * 64, Hbuf + (size_t)TOT * 64, dis + TOT, ei2, ei2 + Ec);

    // Layer 2 (64 -> 64)
    gemm_k<64, 64, true><<<512, 256, 0, stream>>>(Gbuf, W2, Hbuf);
    initagg_k<64><<<8192, 256, 0, stream>>>(Gbuf, Hbuf, dis, b2);
    scatter_k<64><<<65536, 256, 0, stream>>>(Gbuf, Hbuf, dis, ei1, ei1 + Ec);
    scatter_k<64><<<65536, 256, 0, stream>>>(Gbuf + (size_t)TOT * 64, Hbuf + (size_t)TOT * 64, dis + TOT, ei2, ei2 + Ec);

    // Layer 3 (64 -> 32), no output relu
    gemm_k<64, 32, true><<<512, 256, 0, stream>>>(Gbuf, W3, Hbuf);
    initagg_k<32><<<4096, 256, 0, stream>>>(Gbuf, Hbuf, dis, b3);
    scatter_k<32><<<32768, 256, 0, stream>>>(Gbuf, Hbuf, dis, ei1, ei1 + Ec);
    scatter_k<32><<<32768, 256, 0, stream>>>(Gbuf + (size_t)TOT * 32, Hbuf + (size_t)TOT * 32, dis + TOT, ei2, ei2 + Ec);

    // Pooling, histogram, head
    attpool_k<<<256, 256, 0, stream>>>(Gbuf, cnt, st, attW, pool);
    hist_k<<<128, 256, 0, stream>>>(Gbuf, Gbuf + (size_t)TOT * 32, cnt, st, hist);
    final_k<<<128, 64, 0, stream>>>(pool, hist, ntnW, ntnV, ntnb, fc1W, fc1b, scW, scb, out);
}

// Round 2
// 1547.559 us; speedup vs baseline: 3.5808x; 3.5808x over previous
//
#include <hip/hip_runtime.h>
#include <hip/hip_bf16.h>

// Problem constants (fixed by setup_inputs)
constexpr int    TOT = 65536;        // nodes per side
constexpr int    TOT2 = 131072;      // both sides
constexpr int    F3c = 32;
constexpr long long Ec = 16LL * TOT; // 1048576 edges per side

// ---------------- small utility kernels ----------------
__global__ void degcnti_k(int* __restrict__ deg, const int* __restrict__ dst) {
    int t = blockIdx.x * 256 + threadIdx.x;
    atomicAdd(&deg[dst[t]], 1);
}

__global__ void dis_k(float* __restrict__ dis, const int* __restrict__ deg) {
    int t = blockIdx.x * 256 + threadIdx.x;
    if (t < TOT2) dis[t] = rsqrtf((float)deg[t] + 1.0f);
}

__global__ void bcount_k(int* __restrict__ cnt, const int* __restrict__ batch) {
    int t = blockIdx.x * 256 + threadIdx.x;
    atomicAdd(&cnt[batch[t]], 1);
}

__global__ void scan_k(const int* __restrict__ cnt, int* __restrict__ st) {
    if (threadIdx.x < 2) {
        int o = 0;
        for (int q = 0; q < 128; ++q) { st[threadIdx.x * 128 + q] = o; o += cnt[threadIdx.x * 128 + q]; }
    }
}

// Exclusive scan of 65536 degrees per side -> global rowptr (side1 offset by Ec).
// One block of 1024 threads per side; each thread owns 64 contiguous elements.
__global__ __launch_bounds__(1024) void scan_side_k(const int* __restrict__ deg, int* __restrict__ rowptr) {
    const int side = blockIdx.x;
    const int* dg = deg + side * TOT;
    __shared__ int wsum[16];
    const int t = threadIdx.x, lane = t & 63, wid = t >> 6;
    const int base = t * 64;
    int run = 0;
    for (int q = 0; q < 64; ++q) run += dg[base + q];
    int inc = run;
#pragma unroll
    for (int d = 1; d < 64; d <<= 1) { int n = __shfl_up(inc, d, 64); if (lane >= d) inc += n; }
    if (lane == 63) wsum[wid] = inc;
    __syncthreads();
    if (t == 0) { int o = 0; for (int q = 0; q < 16; ++q) { int x = wsum[q]; wsum[q] = o; o += x; } }
    __syncthreads();
    int off = wsum[wid] + inc - run + side * (int)Ec;   // global slot offset
    int* rp = rowptr + side * TOT;
    for (int q = 0; q < 64; ++q) { int v = dg[base + q]; rp[base + q] = off; off += v; }
    if (side == 1 && t == 1023) rowptr[TOT2] = off;
}

__global__ void curcpy_k(const int* __restrict__ rowptr, int* __restrict__ cursor) {
    int t = blockIdx.x * 256 + threadIdx.x;
    if (t < TOT2) cursor[t] = rowptr[t];
}

// Fill CSR slots: csr_src = global source row, csr_w = dis[s]*dis[d]
__global__ void csrfill_k(const int* __restrict__ src, const int* __restrict__ dst,
                          const float* __restrict__ dis, int* __restrict__ cursor,
                          int* __restrict__ csr_src, float* __restrict__ csr_w, int base) {
    int e = blockIdx.x * 256 + threadIdx.x;
    int s = src[e] + base, d = dst[e] + base;
    int slot = atomicAdd(&cursor[d], 1);
    csr_src[slot] = s;
    csr_w[slot] = dis[s] * dis[d];
}

// ---------------- GEMM: out[M,NC] = (relu?)X[M,K] @ W[K,NC] ----------------
template<int K, int NC, bool RELU>
__global__ __launch_bounds__(256) void gemm_k(const float* __restrict__ X,
                                              const float* __restrict__ W,
                                              float* __restrict__ out) {
    __shared__ float Ws[K * NC];
    const int tid = threadIdx.x;
    constexpr int WE4 = K * NC / 1024;
    {
        const float4* Wg = (const float4*)W;
        float4* Wp = (float4*)Ws;
#pragma unroll
        for (int it = 0; it < WE4; ++it) Wp[tid + it * 256] = Wg[tid + it * 256];
    }
    __syncthreads();
    const size_t row = (size_t)blockIdx.x * 256 + tid;
    const float4* Xr = (const float4*)(X + row * K);
    float acc[NC];
#pragma unroll
    for (int j = 0; j < NC; ++j) acc[j] = 0.f;
#pragma unroll 2
    for (int k4 = 0; k4 < K / 4; ++k4) {
        float4 xv = Xr[k4];
        if (RELU) {
            xv.x = fmaxf(xv.x, 0.f); xv.y = fmaxf(xv.y, 0.f);
            xv.z = fmaxf(xv.z, 0.f); xv.w = fmaxf(xv.w, 0.f);
        }
        const float xs[4] = {xv.x, xv.y, xv.z, xv.w};
#pragma unroll
        for (int kk = 0; kk < 4; ++kk) {
#pragma unroll
            for (int j4 = 0; j4 < NC / 4; ++j4) {
                float4 wv = *(const float4*)&Ws[(k4 * 4 + kk) * NC + j4 * 4];
                acc[j4 * 4 + 0] += xs[kk] * wv.x;
                acc[j4 * 4 + 1] += xs[kk] * wv.y;
                acc[j4 * 4 + 2] += xs[kk] * wv.z;
                acc[j4 * 4 + 3] += xs[kk] * wv.w;
            }
        }
    }
    float4* Or = (float4*)(out + row * NC);
#pragma unroll
    for (int j4 = 0; j4 < NC / 4; ++j4)
        Or[j4] = make_float4(acc[j4 * 4], acc[j4 * 4 + 1], acc[j4 * 4 + 2], acc[j4 * 4 + 3]);
}

// ---------------- GCN aggregation: CSR gather (replaces initagg+scatter) ----------------
// out[i] = h[i]*dis[i]^2 + bias + sum_{e in csr[i]} h[csr_src[e]] * csr_w[e]
template<int NC>
__global__ __launch_bounds__(256) void gather_k(float* __restrict__ out, const float* __restrict__ h,
                                                const float* __restrict__ dis, const float* __restrict__ bias,
                                                const int* __restrict__ rowptr, const int* __restrict__ csr_src,
                                                const float* __restrict__ csr_w) {
    constexpr int NPB = 256 / NC;
    const int tid = threadIdx.x;
    const int c = tid & (NC - 1);
    const int node = blockIdx.x * NPB + tid / NC;
    const float dv = dis[node];
    float acc = h[(size_t)node * NC + c] * dv * dv + bias[c];
    int e = rowptr[node];
    const int e1 = rowptr[node + 1];
    for (; e + 1 < e1; e += 2) {
        int s0 = csr_src[e], s1 = csr_src[e + 1];
        float w0 = csr_w[e], w1 = csr_w[e + 1];
        float h0 = h[(size_t)s0 * NC + c];
        float h1 = h[(size_t)s1 * NC + c];
        acc += h0 * w0 + h1 * w1;
    }
    if (e < e1) acc += h[(size_t)csr_src[e] * NC + c] * csr_w[e];
    out[(size_t)node * NC + c] = acc;
}

// ---------------- attention pooling (one block per (side,graph)) ----------------
__global__ __launch_bounds__(256) void attpool_k(const float* __restrict__ af,
                                                 const int* __restrict__ cnt, const int* __restrict__ st,
                                                 const float* __restrict__ attW, float* __restrict__ pool) {
    const int side = blockIdx.x >> 7, b = blockIdx.x & 127;
    const float* h = af + (size_t)side * TOT * F3c;
    const int c = cnt[side * 128 + b], s0 = st[side * 128 + b];
    const int f = threadIdx.x & 31, grp = threadIdx.x >> 5;
    __shared__ float red[8][32];
    __shared__ float mhS[32], tS[32];
    float acc = 0.f;
    for (int i = grp; i < c; i += 8) acc += h[(size_t)(s0 + i) * F3c + f];
    red[grp][f] = acc;
    __syncthreads();
    if (threadIdx.x < 32) { float tt = 0; for (int g = 0; g < 8; ++g) tt += red[g][f]; mhS[f] = tt / (float)c; }
    __syncthreads();
    if (threadIdx.x < 32) {
        float g = 0;
        for (int k = 0; k < 32; ++k) g += mhS[k] * attW[k * 32 + f];
        tS[f] = tanhf(g);
    }
    __syncthreads();
    const float tf = tS[f];
    acc = 0.f;
    for (int i = grp; i < c; i += 8) {
        float hv = h[(size_t)(s0 + i) * F3c + f];
        float pr = hv * tf;
#pragma unroll
        for (int m = 16; m; m >>= 1) pr += __shfl_xor(pr, m, 32);
        float sA = 1.f / (1.f + expf(-pr));
        acc += hv * sA;
    }
    __syncthreads();
    red[grp][f] = acc;
    __syncthreads();
    if (threadIdx.x < 32) {
        float tt = 0; for (int g = 0; g < 8; ++g) tt += red[g][f];
        pool[(size_t)(side * 128 + b) * 32 + f] = tt;
    }
}

// ---------------- histogram (one block per graph pair) ----------------
__global__ __launch_bounds__(256) void hist_k(const float* __restrict__ af1,
                                              const float* __restrict__ af2,
                                              const int* __restrict__ cnt, const int* __restrict__ st,
                                              float* __restrict__ hist) {
    const int b = blockIdx.x;
    const int c1 = cnt[b], c2 = cnt[128 + b];
    const int s1 = st[b], s2 = st[128 + b];
    const int nn = max(c1, c2);
    __shared__ float D2[256 * 32];
    __shared__ int   hloc[256 * 17];
    __shared__ float redn[256], redx[256];
    __shared__ float sMn, sRng;
    const int tid = threadIdx.x;
#pragma unroll
    for (int q = 0; q < 17; ++q) hloc[tid * 17 + q] = 0;
    float lmn = 1e30f, lmx = -1e30f;
    float vMn = 0.f, vRng = 1.f;
    for (int pass = 0; pass < 2; ++pass) {
        for (int jh = 0; jh < 2; ++jh) {
            __syncthreads();
            for (int e = tid; e < 256 * 8; e += 256) {
                int j = e >> 3, q4 = (e & 7) * 4;
                int jg = jh * 256 + j;
                float4 v = make_float4(0.f, 0.f, 0.f, 0.f);
                if (jg < c2) v = *(const float4*)&af2[((size_t)(s2 + jg)) * 32 + q4];
                *(float4*)&D2[j * 32 + q4] = v;
            }
            __syncthreads();
            int jcnt = nn - jh * 256; jcnt = jcnt < 0 ? 0 : (jcnt > 256 ? 256 : jcnt);
            for (int ih = 0; ih < 2; ++ih) {
                const int i = ih * 256 + tid;
                if (i >= nn) continue;
                float r[32];
                if (i < c1) {
                    const float4* rp = (const float4*)&af1[((size_t)(s1 + i)) * 32];
#pragma unroll
                    for (int q = 0; q < 8; ++q) {
                        float4 v = rp[q];
                        r[q * 4] = v.x; r[q * 4 + 1] = v.y; r[q * 4 + 2] = v.z; r[q * 4 + 3] = v.w;
                    }
                } else {
#pragma unroll
                    for (int q = 0; q < 32; ++q) r[q] = 0.f;
                }
                for (int j = 0; j < jcnt; ++j) {
                    float d = 0.f;
#pragma unroll
                    for (int k = 0; k < 32; ++k) d += r[k] * D2[j * 32 + k];
                    if (pass == 0) { lmn = fminf(lmn, d); lmx = fmaxf(lmx, d); }
                    else {
                        float v = 1.f / (1.f + expf(-d));
                        float qq = (v - vMn) / vRng * 16.f;
                        int bi = (int)floorf(qq);
                        bi = bi < 0 ? 0 : (bi > 15 ? 15 : bi);
                        hloc[tid * 17 + bi] += 1;
                    }
                }
            }
        }
        if (pass == 0) {
            redn[tid] = lmn; redx[tid] = lmx;
            __syncthreads();
            for (int sr = 128; sr; sr >>= 1) {
                if (tid < sr) {
                    redn[tid] = fminf(redn[tid], redn[tid + sr]);
                    redx[tid] = fmaxf(redx[tid], redx[tid + sr]);
                }
                __syncthreads();
            }
            if (tid == 0) {
                float a = 1.f / (1.f + expf(-redn[0]));
                float bb = 1.f / (1.f + expf(-redx[0]));
                sMn = a; sRng = (bb > a) ? (bb - a) : 1.f;
            }
            __syncthreads();
            vMn = sMn; vRng = sRng;
        }
    }
    __syncthreads();
    __shared__ float binf[16];
    if (tid < 16) {
        int ssum = 0;
        for (int t2 = 0; t2 < 256; ++t2) ssum += hloc[t2 * 17 + tid];
        binf[tid] = (float)ssum;
    }
    __syncthreads();
    if (tid < 16) {
        float tot = 0; for (int q = 0; q < 16; ++q) tot += binf[q];
        hist[(size_t)b * 16 + tid] = binf[tid] / tot;
    }
}

// ---------------- NTN + final MLP (one block per graph) ----------------
__global__ __launch_bounds__(64) void final_k(const float* __restrict__ pool, const float* __restrict__ hist,
                                              const float* __restrict__ ntnW, const float* __restrict__ ntnV,
                                              const float* __restrict__ ntnb, const float* __restrict__ fc1W,
                                              const float* __restrict__ fc1b, const float* __restrict__ scW,
                                              const float* __restrict__ scb, float* __restrict__ out) {
    const int b = blockIdx.x;
    const int tid = threadIdx.x;
    __shared__ float P1[32], P2[32], feat[32], red[64];
    if (tid < 32) { P1[tid] = pool[b * 32 + tid]; P2[tid] = pool[4096 + b * 32 + tid]; }
    __syncthreads();
    const int k = tid & 15, part = tid >> 4;
    float acc = 0.f;
    for (int i = part * 8; i < part * 8 + 8; ++i) {
        float p1i = P1[i];
        for (int j = 0; j < 32; ++j) acc += p1i * P2[j] * ntnW[(i * 32 + j) * 16 + k];
    }
    red[tid] = acc;
    __syncthreads();
    if (tid < 16) {
        float bl = red[tid] + red[16 + tid] + red[32 + tid] + red[48 + tid];
        float blk = ntnb[tid];
        for (int i = 0; i < 32; ++i) blk += P1[i] * ntnV[tid * 64 + i];
        for (int j = 0; j < 32; ++j) blk += P2[j] * ntnV[tid * 64 + 32 + j];
        feat[tid] = fmaxf(bl + blk, 0.f);
        feat[16 + tid] = hist[b * 16 + tid];
    }
    __syncthreads();
    if (tid < 16) {
        float h = fc1b[tid];
        for (int f = 0; f < 32; ++f) h += feat[f] * fc1W[f * 16 + tid];
        red[tid] = fmaxf(h, 0.f);
    }
    __syncthreads();
    if (tid == 0) {
        float o = scb[0];
        for (int j = 0; j < 16; ++j) o += red[j] * scW[j];
        out[b] = 1.f / (1.f + expf(-o));
    }
}

// ---------------- launch ----------------
extern "C" void kernel_launch(void* const* d_in, const int* in_sizes, int n_in,
                              void* d_out, int out_size, void* d_ws, size_t ws_size,
                              hipStream_t stream) {
    const float* x1   = (const float*)d_in[0];
    const float* x2   = (const float*)d_in[1];
    const int*   ei1  = (const int*)d_in[2];
    const int*   ei2  = (const int*)d_in[3];
    const int*   bat1 = (const int*)d_in[4];
    const int*   bat2 = (const int*)d_in[5];
    const float* W1   = (const float*)d_in[6];
    const float* b1   = (const float*)d_in[7];
    const float* W2   = (const float*)d_in[8];
    const float* b2   = (const float*)d_in[9];
    const float* W3   = (const float*)d_in[10];
    const float* b3   = (const float*)d_in[11];
    const float* attW = (const float*)d_in[12];
    const float* ntnW = (const float*)d_in[13];
    const float* ntnV = (const float*)d_in[14];
    const float* ntnb = (const float*)d_in[15];
    const float* fc1W = (const float*)d_in[16];
    const float* fc1b = (const float*)d_in[17];
    const float* scW  = (const float*)d_in[18];
    const float* scb  = (const float*)d_in[19];
    float* out = (float*)d_out;

    // workspace layout (~85 MB)
    float* Hbuf   = (float*)d_ws;                        // 131072*64 f32
    float* Gbuf   = Hbuf + (size_t)TOT2 * 64;            // 131072*64 f32
    float* dis    = Gbuf + (size_t)TOT2 * 64;            // 131072
    int*   deg    = (int*)(dis + TOT2);                  // 131072
    int*   rowptr = deg + TOT2;                          // 131073
    int*   cursor = rowptr + TOT2 + 1;                   // 131072
    int*   csrs   = cursor + TOT2;                       // 2*1048576
    float* csrw   = (float*)(csrs + 2 * (size_t)Ec);     // 2*1048576
    int*   cnt    = (int*)(csrw + 2 * (size_t)Ec);       // 256
    int*   st     = cnt + 256;                           // 256
    float* pool   = (float*)(st + 256);                  // 8192
    float* hist   = pool + 8192;                         // 2048

    const int Eb = (int)(Ec / 256);                      // 4096 blocks over edges

    hipMemsetAsync(deg, 0, TOT2 * sizeof(int), stream);
    hipMemsetAsync(cnt, 0, 256 * sizeof(int), stream);
    degcnti_k<<<Eb, 256, 0, stream>>>(deg,       ei1 + Ec);   // dst = ei[1]
    degcnti_k<<<Eb, 256, 0, stream>>>(deg + TOT, ei2 + Ec);
    bcount_k<<<256, 256, 0, stream>>>(cnt,       bat1);
    bcount_k<<<256, 256, 0, stream>>>(cnt + 128, bat2);
    dis_k<<<512, 256, 0, stream>>>(dis, deg);
    scan_k<<<1, 64, 0, stream>>>(cnt, st);
    scan_side_k<<<2, 1024, 0, stream>>>(deg, rowptr);
    curcpy_k<<<512, 256, 0, stream>>>(rowptr, cursor);
    csrfill_k<<<Eb, 256, 0, stream>>>(ei1, ei1 + Ec, dis, cursor, csrs, csrw, 0);
    csrfill_k<<<Eb, 256, 0, stream>>>(ei2, ei2 + Ec, dis, cursor, csrs, csrw, TOT);

    // Layer 1 (K=128 -> 64)
    gemm_k<128, 64, false><<<256, 256, 0, stream>>>(x1, W1, Hbuf);
    gemm_k<128, 64, false><<<256, 256, 0, stream>>>(x2, W1, Hbuf + (size_t)TOT * 64);
    gather_k<64><<<TOT2 / 4, 256, 0, stream>>>(Gbuf, Hbuf, dis, b1, rowptr, csrs, csrw);

    // Layer 2 (64 -> 64), relu fused into GEMM load
    gemm_k<64, 64, true><<<512, 256, 0, stream>>>(Gbuf, W2, Hbuf);
    gather_k<64><<<TOT2 / 4, 256, 0, stream>>>(Gbuf, Hbuf, dis, b2, rowptr, csrs, csrw);

    // Layer 3 (64 -> 32)
    gemm_k<64, 32, true><<<512, 256, 0, stream>>>(Gbuf, W3, Hbuf);
    gather_k<32><<<TOT2 / 8, 256, 0, stream>>>(Gbuf, Hbuf, dis, b3, rowptr, csrs, csrw);

    // Pooling, histogram, head
    attpool_k<<<256, 256, 0, stream>>>(Gbuf, cnt, st, attW, pool);
    hist_k<<<128, 256, 0, stream>>>(Gbuf, Gbuf + (size_t)TOT * 32, cnt, st, hist);
    final_k<<<128, 64, 0, stream>>>(pool, hist, ntnW, ntnV, ntnb, fc1W, fc1b, scW, scb, out);
}

// Round 3
// 1164.012 us; speedup vs baseline: 4.7607x; 1.3295x over previous
//
#include <hip/hip_runtime.h>
#include <hip/hip_bf16.h>

// Problem constants (fixed by setup_inputs)
constexpr int    TOT = 65536;        // nodes per side
constexpr int    TOT2 = 131072;      // both sides
constexpr int    F3c = 32;
constexpr long long Ec = 16LL * TOT; // 1048576 edges per side

__device__ __forceinline__ float sigm(float x) { return 1.f / (1.f + __expf(-x)); }

// ---------------- small utility kernels ----------------
__global__ void degcnti_k(int* __restrict__ deg, const int* __restrict__ dst) {
    int t = blockIdx.x * 256 + threadIdx.x;
    atomicAdd(&deg[dst[t]], 1);
}

__global__ void dis_k(float* __restrict__ dis, const int* __restrict__ deg) {
    int t = blockIdx.x * 256 + threadIdx.x;
    if (t < TOT2) dis[t] = rsqrtf((float)deg[t] + 1.0f);
}

__global__ void bcount_k(int* __restrict__ cnt, const int* __restrict__ batch) {
    int t = blockIdx.x * 256 + threadIdx.x;
    atomicAdd(&cnt[batch[t]], 1);
}

__global__ void scan_k(const int* __restrict__ cnt, int* __restrict__ st) {
    if (threadIdx.x < 2) {
        int o = 0;
        for (int q = 0; q < 128; ++q) { st[threadIdx.x * 128 + q] = o; o += cnt[threadIdx.x * 128 + q]; }
    }
}

// Exclusive scan of 65536 degrees per side -> global rowptr (side1 offset by Ec).
__global__ __launch_bounds__(1024) void scan_side_k(const int* __restrict__ deg, int* __restrict__ rowptr) {
    const int side = blockIdx.x;
    const int* dg = deg + side * TOT;
    __shared__ int wsum[16];
    const int t = threadIdx.x, lane = t & 63, wid = t >> 6;
    const int base = t * 64;
    int run = 0;
    for (int q = 0; q < 64; ++q) run += dg[base + q];
    int inc = run;
#pragma unroll
    for (int d = 1; d < 64; d <<= 1) { int n = __shfl_up(inc, d, 64); if (lane >= d) inc += n; }
    if (lane == 63) wsum[wid] = inc;
    __syncthreads();
    if (t == 0) { int o = 0; for (int q = 0; q < 16; ++q) { int x = wsum[q]; wsum[q] = o; o += x; } }
    __syncthreads();
    int off = wsum[wid] + inc - run + side * (int)Ec;
    int* rp = rowptr + side * TOT;
    for (int q = 0; q < 64; ++q) { int v = dg[base + q]; rp[base + q] = off; off += v; }
    if (side == 1 && t == 1023) rowptr[TOT2] = off;
}

__global__ void curcpy_k(const int* __restrict__ rowptr, int* __restrict__ cursor) {
    int t = blockIdx.x * 256 + threadIdx.x;
    if (t < TOT2) cursor[t] = rowptr[t];
}

__global__ void csrfill_k(const int* __restrict__ src, const int* __restrict__ dst,
                          const float* __restrict__ dis, int* __restrict__ cursor,
                          int* __restrict__ csr_src, float* __restrict__ csr_w, int base) {
    int e = blockIdx.x * 256 + threadIdx.x;
    int s = src[e] + base, d = dst[e] + base;
    int slot = atomicAdd(&cursor[d], 1);
    csr_src[slot] = s;
    csr_w[slot] = dis[s] * dis[d];
}

// ---------------- GEMM: out[M,NC] = (relu?)X[M,K] @ W[K,NC] ----------------
template<int K, int NC, bool RELU>
__global__ __launch_bounds__(256) void gemm_k(const float* __restrict__ X,
                                              const float* __restrict__ W,
                                              float* __restrict__ out) {
    __shared__ float Ws[K * NC];
    const int tid = threadIdx.x;
    constexpr int WE4 = K * NC / 1024;
    {
        const float4* Wg = (const float4*)W;
        float4* Wp = (float4*)Ws;
#pragma unroll
        for (int it = 0; it < WE4; ++it) Wp[tid + it * 256] = Wg[tid + it * 256];
    }
    __syncthreads();
    const size_t row = (size_t)blockIdx.x * 256 + tid;
    const float4* Xr = (const float4*)(X + row * K);
    float acc[NC];
#pragma unroll
    for (int j = 0; j < NC; ++j) acc[j] = 0.f;
#pragma unroll 2
    for (int k4 = 0; k4 < K / 4; ++k4) {
        float4 xv = Xr[k4];
        if (RELU) {
            xv.x = fmaxf(xv.x, 0.f); xv.y = fmaxf(xv.y, 0.f);
            xv.z = fmaxf(xv.z, 0.f); xv.w = fmaxf(xv.w, 0.f);
        }
        const float xs[4] = {xv.x, xv.y, xv.z, xv.w};
#pragma unroll
        for (int kk = 0; kk < 4; ++kk) {
#pragma unroll
            for (int j4 = 0; j4 < NC / 4; ++j4) {
                float4 wv = *(const float4*)&Ws[(k4 * 4 + kk) * NC + j4 * 4];
                acc[j4 * 4 + 0] += xs[kk] * wv.x;
                acc[j4 * 4 + 1] += xs[kk] * wv.y;
                acc[j4 * 4 + 2] += xs[kk] * wv.z;
                acc[j4 * 4 + 3] += xs[kk] * wv.w;
            }
        }
    }
    float4* Or = (float4*)(out + row * NC);
#pragma unroll
    for (int j4 = 0; j4 < NC / 4; ++j4)
        Or[j4] = make_float4(acc[j4 * 4], acc[j4 * 4 + 1], acc[j4 * 4 + 2], acc[j4 * 4 + 3]);
}

// ---------------- GCN aggregation: CSR gather ----------------
template<int NC>
__global__ __launch_bounds__(256) void gather_k(float* __restrict__ out, const float* __restrict__ h,
                                                const float* __restrict__ dis, const float* __restrict__ bias,
                                                const int* __restrict__ rowptr, const int* __restrict__ csr_src,
                                                const float* __restrict__ csr_w) {
    constexpr int NPB = 256 / NC;
    const int tid = threadIdx.x;
    const int c = tid & (NC - 1);
    const int node = blockIdx.x * NPB + tid / NC;
    const float dv = dis[node];
    float acc = h[(size_t)node * NC + c] * dv * dv + bias[c];
    int e = rowptr[node];
    const int e1 = rowptr[node + 1];
    for (; e + 1 < e1; e += 2) {
        int s0 = csr_src[e], s1 = csr_src[e + 1];
        float w0 = csr_w[e], w1 = csr_w[e + 1];
        float h0 = h[(size_t)s0 * NC + c];
        float h1 = h[(size_t)s1 * NC + c];
        acc += h0 * w0 + h1 * w1;
    }
    if (e < e1) acc += h[(size_t)csr_src[e] * NC + c] * csr_w[e];
    out[(size_t)node * NC + c] = acc;
}

// ---------------- attention pooling (one block per (side,graph)) ----------------
__global__ __launch_bounds__(256) void attpool_k(const float* __restrict__ af,
                                                 const int* __restrict__ cnt, const int* __restrict__ st,
                                                 const float* __restrict__ attW, float* __restrict__ pool) {
    const int side = blockIdx.x >> 7, b = blockIdx.x & 127;
    const float* h = af + (size_t)side * TOT * F3c;
    const int c = cnt[side * 128 + b], s0 = st[side * 128 + b];
    const int f = threadIdx.x & 31, grp = threadIdx.x >> 5;
    __shared__ float red[8][32];
    __shared__ float mhS[32], tS[32];
    float acc = 0.f;
    for (int i = grp; i < c; i += 8) acc += h[(size_t)(s0 + i) * F3c + f];
    red[grp][f] = acc;
    __syncthreads();
    if (threadIdx.x < 32) { float tt = 0; for (int g = 0; g < 8; ++g) tt += red[g][f]; mhS[f] = tt / (float)c; }
    __syncthreads();
    if (threadIdx.x < 32) {
        float g = 0;
        for (int k = 0; k < 32; ++k) g += mhS[k] * attW[k * 32 + f];
        tS[f] = tanhf(g);
    }
    __syncthreads();
    const float tf = tS[f];
    acc = 0.f;
    for (int i = grp; i < c; i += 8) {
        float hv = h[(size_t)(s0 + i) * F3c + f];
        float pr = hv * tf;
#pragma unroll
        for (int m = 16; m; m >>= 1) pr += __shfl_xor(pr, m, 32);
        float sA = 1.f / (1.f + expf(-pr));
        acc += hv * sA;
    }
    __syncthreads();
    red[grp][f] = acc;
    __syncthreads();
    if (threadIdx.x < 32) {
        float tt = 0; for (int g = 0; g < 8; ++g) tt += red[g][f];
        pool[(size_t)(side * 128 + b) * 32 + f] = tt;
    }
}

// ---------------- histogram pass 1: per-(graph, i-tile) raw-dot min/max ----------------
// grid = 128*4. Each thread owns 2 i-rows (regs) and a 64-wide j segment of the staged half.
__global__ __launch_bounds__(256) void minmax_k(const float* __restrict__ af1,
                                                const float* __restrict__ af2,
                                                const int* __restrict__ cnt, const int* __restrict__ st,
                                                float* __restrict__ bmn, float* __restrict__ bmx) {
    const int b = blockIdx.x >> 2, it = blockIdx.x & 3;
    const int c1 = cnt[b], c2 = cnt[128 + b];
    const int s1 = st[b], s2 = st[128 + b];
    const int nn = max(c1, c2);
    __shared__ float D2[256 * 32];
    __shared__ float redn[256], redx[256];
    const int tid = threadIdx.x;
    const int irow = tid & 63, jseg = tid >> 6;   // jseg uniform per wave
    const int i0 = it * 128 + irow, i1 = i0 + 64;
    const bool v0 = i0 < nn, v1 = i1 < nn;
    float r0[32], r1[32];
    {
        const float4* p0 = (const float4*)&af1[(size_t)(s1 + i0) * 32];
        const float4* p1 = (const float4*)&af1[(size_t)(s1 + i1) * 32];
#pragma unroll
        for (int q = 0; q < 8; ++q) {
            float4 a = (i0 < c1) ? p0[q] : make_float4(0, 0, 0, 0);
            float4 c = (i1 < c1) ? p1[q] : make_float4(0, 0, 0, 0);
            r0[q * 4] = a.x; r0[q * 4 + 1] = a.y; r0[q * 4 + 2] = a.z; r0[q * 4 + 3] = a.w;
            r1[q * 4] = c.x; r1[q * 4 + 1] = c.y; r1[q * 4 + 2] = c.z; r1[q * 4 + 3] = c.w;
        }
    }
    float lmn = 1e30f, lmx = -1e30f;
    for (int jh = 0; jh < 2; ++jh) {
        __syncthreads();
        for (int e = tid; e < 2048; e += 256) {
            int j = e >> 3, q4 = (e & 7) * 4;
            int jg = jh * 256 + j;
            float4 v = (jg < c2) ? *(const float4*)&af2[(size_t)(s2 + jg) * 32 + q4]
                                 : make_float4(0, 0, 0, 0);
            *(float4*)&D2[j * 32 + q4] = v;
        }
        __syncthreads();
        const int jbeg = jseg * 64;
        const int jend = min(jbeg + 64, nn - jh * 256);
        for (int j = jbeg; j < jend; ++j) {
            float a0 = 0, a1 = 0, a2 = 0, a3 = 0, b0 = 0, b1 = 0, b2 = 0, b3 = 0;
#pragma unroll
            for (int k = 0; k < 8; ++k) {
                float4 w = *(const float4*)&D2[j * 32 + k * 4];
                a0 += r0[k * 4] * w.x; a1 += r0[k * 4 + 1] * w.y;
                a2 += r0[k * 4 + 2] * w.z; a3 += r0[k * 4 + 3] * w.w;
                b0 += r1[k * 4] * w.x; b1 += r1[k * 4 + 1] * w.y;
                b2 += r1[k * 4 + 2] * w.z; b3 += r1[k * 4 + 3] * w.w;
            }
            float d0 = (a0 + a1) + (a2 + a3);
            float d1 = (b0 + b1) + (b2 + b3);
            if (v0) { lmn = fminf(lmn, d0); lmx = fmaxf(lmx, d0); }
            if (v1) { lmn = fminf(lmn, d1); lmx = fmaxf(lmx, d1); }
        }
    }
    redn[tid] = lmn; redx[tid] = lmx;
    __syncthreads();
    for (int sr = 128; sr; sr >>= 1) {
        if (tid < sr) {
            redn[tid] = fminf(redn[tid], redn[tid + sr]);
            redx[tid] = fmaxf(redx[tid], redx[tid + sr]);
        }
        __syncthreads();
    }
    if (tid == 0) { bmn[blockIdx.x] = redn[0]; bmx[blockIdx.x] = redx[0]; }
}

// ---------------- histogram pass 2: bin + accumulate ----------------
__global__ __launch_bounds__(256) void bin_k(const float* __restrict__ af1,
                                             const float* __restrict__ af2,
                                             const int* __restrict__ cnt, const int* __restrict__ st,
                                             const float* __restrict__ bmn, const float* __restrict__ bmx,
                                             float* __restrict__ hist) {
    const int b = blockIdx.x >> 2, it = blockIdx.x & 3;
    const int c1 = cnt[b], c2 = cnt[128 + b];
    const int s1 = st[b], s2 = st[128 + b];
    const int nn = max(c1, c2);
    __shared__ float D2[256 * 32];
    __shared__ int hloc[256 * 17];
    __shared__ int part[64];
    const int tid = threadIdx.x;
    const int irow = tid & 63, jseg = tid >> 6;
    const int i0 = it * 128 + irow, i1 = i0 + 64;
    const bool v0 = i0 < nn, v1 = i1 < nn;
    // bin range from pass-1 partials (sigmoid space; monotonic)
    float dmn = 1e30f, dmx = -1e30f;
#pragma unroll
    for (int q = 0; q < 4; ++q) {
        dmn = fminf(dmn, bmn[(b << 2) + q]);
        dmx = fmaxf(dmx, bmx[(b << 2) + q]);
    }
    const float vMn = sigm(dmn), vMx = sigm(dmx);
    const float vScale = 16.f / ((vMx > vMn) ? (vMx - vMn) : 1.f);
    float r0[32], r1[32];
    {
        const float4* p0 = (const float4*)&af1[(size_t)(s1 + i0) * 32];
        const float4* p1 = (const float4*)&af1[(size_t)(s1 + i1) * 32];
#pragma unroll
        for (int q = 0; q < 8; ++q) {
            float4 a = (i0 < c1) ? p0[q] : make_float4(0, 0, 0, 0);
            float4 c = (i1 < c1) ? p1[q] : make_float4(0, 0, 0, 0);
            r0[q * 4] = a.x; r0[q * 4 + 1] = a.y; r0[q * 4 + 2] = a.z; r0[q * 4 + 3] = a.w;
            r1[q * 4] = c.x; r1[q * 4 + 1] = c.y; r1[q * 4 + 2] = c.z; r1[q * 4 + 3] = c.w;
        }
    }
#pragma unroll
    for (int q = 0; q < 17; ++q) hloc[tid * 17 + q] = 0;
    for (int jh = 0; jh < 2; ++jh) {
        __syncthreads();
        for (int e = tid; e < 2048; e += 256) {
            int j = e >> 3, q4 = (e & 7) * 4;
            int jg = jh * 256 + j;
            float4 v = (jg < c2) ? *(const float4*)&af2[(size_t)(s2 + jg) * 32 + q4]
                                 : make_float4(0, 0, 0, 0);
            *(float4*)&D2[j * 32 + q4] = v;
        }
        __syncthreads();
        const int jbeg = jseg * 64;
        const int jend = min(jbeg + 64, nn - jh * 256);
        for (int j = jbeg; j < jend; ++j) {
            float a0 = 0, a1 = 0, a2 = 0, a3 = 0, b0 = 0, b1 = 0, b2 = 0, b3 = 0;
#pragma unroll
            for (int k = 0; k < 8; ++k) {
                float4 w = *(const float4*)&D2[j * 32 + k * 4];
                a0 += r0[k * 4] * w.x; a1 += r0[k * 4 + 1] * w.y;
                a2 += r0[k * 4 + 2] * w.z; a3 += r0[k * 4 + 3] * w.w;
                b0 += r1[k * 4] * w.x; b1 += r1[k * 4 + 1] * w.y;
                b2 += r1[k * 4 + 2] * w.z; b3 += r1[k * 4 + 3] * w.w;
            }
            float d0 = (a0 + a1) + (a2 + a3);
            float d1 = (b0 + b1) + (b2 + b3);
            if (v0) {
                float t = (sigm(d0) - vMn) * vScale;
                int bi = (int)floorf(t);
                bi = bi < 0 ? 0 : (bi > 15 ? 15 : bi);
                hloc[tid * 17 + bi] += 1;
            }
            if (v1) {
                float t = (sigm(d1) - vMn) * vScale;
                int bi = (int)floorf(t);
                bi = bi < 0 ? 0 : (bi > 15 ? 15 : bi);
                hloc[tid * 17 + bi] += 1;
            }
        }
    }
    __syncthreads();
    if (tid < 64) {
        const int bin = tid & 15, q = tid >> 4;
        int s = 0;
        for (int t2 = q * 64; t2 < q * 64 + 64; ++t2) s += hloc[t2 * 17 + bin];
        part[tid] = s;
    }
    __syncthreads();
    if (tid < 16) {
        int s = part[tid] + part[16 + tid] + part[32 + tid] + part[48 + tid];
        atomicAdd(&hist[b * 16 + tid], (float)s);
    }
}

// ---------------- NTN + final MLP (one block per graph) ----------------
__global__ __launch_bounds__(64) void final_k(const float* __restrict__ pool, const float* __restrict__ hist,
                                              const int* __restrict__ cnt,
                                              const float* __restrict__ ntnW, const float* __restrict__ ntnV,
                                              const float* __restrict__ ntnb, const float* __restrict__ fc1W,
                                              const float* __restrict__ fc1b, const float* __restrict__ scW,
                                              const float* __restrict__ scb, float* __restrict__ out) {
    const int b = blockIdx.x;
    const int tid = threadIdx.x;
    __shared__ float P1[32], P2[32], feat[32], red[64];
    if (tid < 32) { P1[tid] = pool[b * 32 + tid]; P2[tid] = pool[4096 + b * 32 + tid]; }
    __syncthreads();
    const int k = tid & 15, part = tid >> 4;
    float acc = 0.f;
    for (int i = part * 8; i < part * 8 + 8; ++i) {
        float p1i = P1[i];
        for (int j = 0; j < 32; ++j) acc += p1i * P2[j] * ntnW[(i * 32 + j) * 16 + k];
    }
    red[tid] = acc;
    __syncthreads();
    if (tid < 16) {
        float bl = red[tid] + red[16 + tid] + red[32 + tid] + red[48 + tid];
        float blk = ntnb[tid];
        for (int i = 0; i < 32; ++i) blk += P1[i] * ntnV[tid * 64 + i];
        for (int j = 0; j < 32; ++j) blk += P2[j] * ntnV[tid * 64 + 32 + j];
        feat[tid] = fmaxf(bl + blk, 0.f);
        const int nn = max(cnt[b], cnt[128 + b]);
        feat[16 + tid] = hist[b * 16 + tid] / (float)(nn * nn);
    }
    __syncthreads();
    if (tid < 16) {
        float h = fc1b[tid];
        for (int f = 0; f < 32; ++f) h += feat[f] * fc1W[f * 16 + tid];
        red[tid] = fmaxf(h, 0.f);
    }
    __syncthreads();
    if (tid == 0) {
        float o = scb[0];
        for (int j = 0; j < 16; ++j) o += red[j] * scW[j];
        out[b] = 1.f / (1.f + expf(-o));
    }
}

// ---------------- launch ----------------
extern "C" void kernel_launch(void* const* d_in, const int* in_sizes, int n_in,
                              void* d_out, int out_size, void* d_ws, size_t ws_size,
                              hipStream_t stream) {
    const float* x1   = (const float*)d_in[0];
    const float* x2   = (const float*)d_in[1];
    const int*   ei1  = (const int*)d_in[2];
    const int*   ei2  = (const int*)d_in[3];
    const int*   bat1 = (const int*)d_in[4];
    const int*   bat2 = (const int*)d_in[5];
    const float* W1   = (const float*)d_in[6];
    const float* b1   = (const float*)d_in[7];
    const float* W2   = (const float*)d_in[8];
    const float* b2   = (const float*)d_in[9];
    const float* W3   = (const float*)d_in[10];
    const float* b3   = (const float*)d_in[11];
    const float* attW = (const float*)d_in[12];
    const float* ntnW = (const float*)d_in[13];
    const float* ntnV = (const float*)d_in[14];
    const float* ntnb = (const float*)d_in[15];
    const float* fc1W = (const float*)d_in[16];
    const float* fc1b = (const float*)d_in[17];
    const float* scW  = (const float*)d_in[18];
    const float* scb  = (const float*)d_in[19];
    float* out = (float*)d_out;

    // workspace layout (~85 MB)
    float* Hbuf   = (float*)d_ws;                        // 131072*64 f32
    float* Gbuf   = Hbuf + (size_t)TOT2 * 64;            // 131072*64 f32
    float* dis    = Gbuf + (size_t)TOT2 * 64;            // 131072
    int*   deg    = (int*)(dis + TOT2);                  // 131072
    int*   rowptr = deg + TOT2;                          // 131073
    int*   cursor = rowptr + TOT2 + 1;                   // 131072
    int*   csrs   = cursor + TOT2;                       // 2*1048576
    float* csrw   = (float*)(csrs + 2 * (size_t)Ec);     // 2*1048576
    int*   cnt    = (int*)(csrw + 2 * (size_t)Ec);       // 256
    int*   st     = cnt + 256;                           // 256
    float* pool   = (float*)(st + 256);                  // 8192
    float* hist   = pool + 8192;                         // 2048
    float* bmn    = hist + 2048;                         // 512
    float* bmx    = bmn + 512;                           // 512

    const int Eb = (int)(Ec / 256);                      // 4096 blocks over edges

    hipMemsetAsync(deg, 0, TOT2 * sizeof(int), stream);
    hipMemsetAsync(cnt, 0, 256 * sizeof(int), stream);
    hipMemsetAsync(hist, 0, 2048 * sizeof(float), stream);
    degcnti_k<<<Eb, 256, 0, stream>>>(deg,       ei1 + Ec);   // dst = ei[1]
    degcnti_k<<<Eb, 256, 0, stream>>>(deg + TOT, ei2 + Ec);
    bcount_k<<<256, 256, 0, stream>>>(cnt,       bat1);
    bcount_k<<<256, 256, 0, stream>>>(cnt + 128, bat2);
    dis_k<<<512, 256, 0, stream>>>(dis, deg);
    scan_k<<<1, 64, 0, stream>>>(cnt, st);
    scan_side_k<<<2, 1024, 0, stream>>>(deg, rowptr);
    curcpy_k<<<512, 256, 0, stream>>>(rowptr, cursor);
    csrfill_k<<<Eb, 256, 0, stream>>>(ei1, ei1 + Ec, dis, cursor, csrs, csrw, 0);
    csrfill_k<<<Eb, 256, 0, stream>>>(ei2, ei2 + Ec, dis, cursor, csrs, csrw, TOT);

    // Layer 1 (K=128 -> 64)
    gemm_k<128, 64, false><<<256, 256, 0, stream>>>(x1, W1, Hbuf);
    gemm_k<128, 64, false><<<256, 256, 0, stream>>>(x2, W1, Hbuf + (size_t)TOT * 64);
    gather_k<64><<<TOT2 / 4, 256, 0, stream>>>(Gbuf, Hbuf, dis, b1, rowptr, csrs, csrw);

    // Layer 2 (64 -> 64), relu fused into GEMM load
    gemm_k<64, 64, true><<<512, 256, 0, stream>>>(Gbuf, W2, Hbuf);
    gather_k<64><<<TOT2 / 4, 256, 0, stream>>>(Gbuf, Hbuf, dis, b2, rowptr, csrs, csrw);

    // Layer 3 (64 -> 32)
    gemm_k<64, 32, true><<<512, 256, 0, stream>>>(Gbuf, W3, Hbuf);
    gather_k<32><<<TOT2 / 8, 256, 0, stream>>>(Gbuf, Hbuf, dis, b3, rowptr, csrs, csrw);

    // Pooling, histogram, head
    attpool_k<<<256, 256, 0, stream>>>(Gbuf, cnt, st, attW, pool);
    minmax_k<<<512, 256, 0, stream>>>(Gbuf, Gbuf + (size_t)TOT * 32, cnt, st, bmn, bmx);
    bin_k<<<512, 256, 0, stream>>>(Gbuf, Gbuf + (size_t)TOT * 32, cnt, st, bmn, bmx, hist);
    final_k<<<128, 64, 0, stream>>>(pool, hist, cnt, ntnW, ntnV, ntnb, fc1W, fc1b, scW, scb, out);
}

// Round 4
// 862.191 us; speedup vs baseline: 6.4272x; 1.3501x over previous
//
#include <hip/hip_runtime.h>
#include <hip/hip_bf16.h>

// Problem constants (fixed by setup_inputs)
constexpr int    TOT = 65536;        // nodes per side
constexpr int    TOT2 = 131072;      // both sides
constexpr int    F3c = 32;
constexpr long long Ec = 16LL * TOT; // 1048576 edges per side

__device__ __forceinline__ float sigm(float x) { return 1.f / (1.f + __expf(-x)); }

// ---------------- small utility kernels ----------------
__global__ void degcnti_k(int* __restrict__ deg, const int* __restrict__ dst) {
    int t = blockIdx.x * 256 + threadIdx.x;
    atomicAdd(&deg[dst[t]], 1);
}

__global__ void dis_k(float* __restrict__ dis, const int* __restrict__ deg) {
    int t = blockIdx.x * 256 + threadIdx.x;
    if (t < TOT2) dis[t] = rsqrtf((float)deg[t] + 1.0f);
}

// batch arrays are sorted (reference's cumsum-based dense batching assumes it):
// st/cnt per (side,graph) via binary search — no atomics.
__global__ void bs_k(const int* __restrict__ b1, const int* __restrict__ b2,
                     int* __restrict__ cnt, int* __restrict__ st) {
    int t = threadIdx.x;                      // 256 threads: side = t>>7, g = t&127
    const int* bat = (t < 128) ? b1 : b2;
    const int g = t & 127;
    int lo = 0, hi = TOT;
    while (lo < hi) { int m = (lo + hi) >> 1; if (bat[m] < g) lo = m + 1; else hi = m; }
    const int s0 = lo;
    hi = TOT;
    while (lo < hi) { int m = (lo + hi) >> 1; if (bat[m] < g + 1) lo = m + 1; else hi = m; }
    st[t] = s0;
    cnt[t] = lo - s0;
}

// Exclusive scan of 65536 degrees per side -> global rowptr (side1 offset by Ec).
__global__ __launch_bounds__(1024) void scan_side_k(const int* __restrict__ deg, int* __restrict__ rowptr) {
    const int side = blockIdx.x;
    const int* dg = deg + side * TOT;
    __shared__ int wsum[16];
    const int t = threadIdx.x, lane = t & 63, wid = t >> 6;
    const int base = t * 64;
    int run = 0;
    for (int q = 0; q < 64; ++q) run += dg[base + q];
    int inc = run;
#pragma unroll
    for (int d = 1; d < 64; d <<= 1) { int n = __shfl_up(inc, d, 64); if (lane >= d) inc += n; }
    if (lane == 63) wsum[wid] = inc;
    __syncthreads();
    if (t == 0) { int o = 0; for (int q = 0; q < 16; ++q) { int x = wsum[q]; wsum[q] = o; o += x; } }
    __syncthreads();
    int off = wsum[wid] + inc - run + side * (int)Ec;
    int* rp = rowptr + side * TOT;
    for (int q = 0; q < 64; ++q) { int v = dg[base + q]; rp[base + q] = off; off += v; }
    if (side == 1 && t == 1023) rowptr[TOT2] = off;
}

__global__ void curcpy_k(const int* __restrict__ rowptr, int* __restrict__ cursor) {
    int t = blockIdx.x * 256 + threadIdx.x;
    if (t < TOT2) cursor[t] = rowptr[t];
}

__global__ void csrfill_k(const int* __restrict__ src, const int* __restrict__ dst,
                          const float* __restrict__ dis, int* __restrict__ cursor,
                          int* __restrict__ csr_src, float* __restrict__ csr_w, int base) {
    int e = blockIdx.x * 256 + threadIdx.x;
    int s = src[e] + base, d = dst[e] + base;
    int slot = atomicAdd(&cursor[d], 1);
    csr_src[slot] = s;
    csr_w[slot] = dis[s] * dis[d];
}

// ---------------- GEMM: out[M,NC] = (relu?)X[M,K] @ W[K,NC] ----------------
template<int K, int NC, bool RELU>
__global__ __launch_bounds__(256) void gemm_k(const float* __restrict__ X,
                                              const float* __restrict__ W,
                                              float* __restrict__ out) {
    __shared__ float Ws[K * NC];
    const int tid = threadIdx.x;
    constexpr int WE4 = K * NC / 1024;
    {
        const float4* Wg = (const float4*)W;
        float4* Wp = (float4*)Ws;
#pragma unroll
        for (int it = 0; it < WE4; ++it) Wp[tid + it * 256] = Wg[tid + it * 256];
    }
    __syncthreads();
    const size_t row = (size_t)blockIdx.x * 256 + tid;
    const float4* Xr = (const float4*)(X + row * K);
    float acc[NC];
#pragma unroll
    for (int j = 0; j < NC; ++j) acc[j] = 0.f;
#pragma unroll 2
    for (int k4 = 0; k4 < K / 4; ++k4) {
        float4 xv = Xr[k4];
        if (RELU) {
            xv.x = fmaxf(xv.x, 0.f); xv.y = fmaxf(xv.y, 0.f);
            xv.z = fmaxf(xv.z, 0.f); xv.w = fmaxf(xv.w, 0.f);
        }
        const float xs[4] = {xv.x, xv.y, xv.z, xv.w};
#pragma unroll
        for (int kk = 0; kk < 4; ++kk) {
#pragma unroll
            for (int j4 = 0; j4 < NC / 4; ++j4) {
                float4 wv = *(const float4*)&Ws[(k4 * 4 + kk) * NC + j4 * 4];
                acc[j4 * 4 + 0] += xs[kk] * wv.x;
                acc[j4 * 4 + 1] += xs[kk] * wv.y;
                acc[j4 * 4 + 2] += xs[kk] * wv.z;
                acc[j4 * 4 + 3] += xs[kk] * wv.w;
            }
        }
    }
    float4* Or = (float4*)(out + row * NC);
#pragma unroll
    for (int j4 = 0; j4 < NC / 4; ++j4)
        Or[j4] = make_float4(acc[j4 * 4], acc[j4 * 4 + 1], acc[j4 * 4 + 2], acc[j4 * 4 + 3]);
}

// ---------------- GCN aggregation: CSR gather ----------------
template<int NC>
__global__ __launch_bounds__(256) void gather_k(float* __restrict__ out, const float* __restrict__ h,
                                                const float* __restrict__ dis, const float* __restrict__ bias,
                                                const int* __restrict__ rowptr, const int* __restrict__ csr_src,
                                                const float* __restrict__ csr_w) {
    constexpr int NPB = 256 / NC;
    const int tid = threadIdx.x;
    const int c = tid & (NC - 1);
    const int node = blockIdx.x * NPB + tid / NC;
    const float dv = dis[node];
    float acc = h[(size_t)node * NC + c] * dv * dv + bias[c];
    int e = rowptr[node];
    const int e1 = rowptr[node + 1];
    for (; e + 1 < e1; e += 2) {
        int s0 = csr_src[e], s1 = csr_src[e + 1];
        float w0 = csr_w[e], w1 = csr_w[e + 1];
        float h0 = h[(size_t)s0 * NC + c];
        float h1 = h[(size_t)s1 * NC + c];
        acc += h0 * w0 + h1 * w1;
    }
    if (e < e1) acc += h[(size_t)csr_src[e] * NC + c] * csr_w[e];
    out[(size_t)node * NC + c] = acc;
}

// ---------------- attention pooling (one block per (side,graph)) ----------------
__global__ __launch_bounds__(256) void attpool_k(const float* __restrict__ af,
                                                 const int* __restrict__ cnt, const int* __restrict__ st,
                                                 const float* __restrict__ attW, float* __restrict__ pool) {
    const int side = blockIdx.x >> 7, b = blockIdx.x & 127;
    const float* h = af + (size_t)side * TOT * F3c;
    const int c = cnt[side * 128 + b], s0 = st[side * 128 + b];
    const int f = threadIdx.x & 31, grp = threadIdx.x >> 5;
    __shared__ float red[8][32];
    __shared__ float mhS[32], tS[32];
    float acc = 0.f;
    for (int i = grp; i < c; i += 8) acc += h[(size_t)(s0 + i) * F3c + f];
    red[grp][f] = acc;
    __syncthreads();
    if (threadIdx.x < 32) { float tt = 0; for (int g = 0; g < 8; ++g) tt += red[g][f]; mhS[f] = tt / (float)c; }
    __syncthreads();
    if (threadIdx.x < 32) {
        float g = 0;
        for (int k = 0; k < 32; ++k) g += mhS[k] * attW[k * 32 + f];
        tS[f] = tanhf(g);
    }
    __syncthreads();
    const float tf = tS[f];
    acc = 0.f;
    for (int i = grp; i < c; i += 8) {
        float hv = h[(size_t)(s0 + i) * F3c + f];
        float pr = hv * tf;
#pragma unroll
        for (int m = 16; m; m >>= 1) pr += __shfl_xor(pr, m, 32);
        float sA = 1.f / (1.f + expf(-pr));
        acc += hv * sA;
    }
    __syncthreads();
    red[grp][f] = acc;
    __syncthreads();
    if (threadIdx.x < 32) {
        float tt = 0; for (int g = 0; g < 8; ++g) tt += red[g][f];
        pool[(size_t)(side * 128 + b) * 32 + f] = tt;
    }
}

// ---------------- histogram pass 1: per-(graph, i-tile) raw-dot min/max ----------------
__global__ __launch_bounds__(256) void minmax_k(const float* __restrict__ af1,
                                                const float* __restrict__ af2,
                                                const int* __restrict__ cnt, const int* __restrict__ st,
                                                float* __restrict__ bmn, float* __restrict__ bmx) {
    const int b = blockIdx.x >> 2, it = blockIdx.x & 3;
    const int c1 = cnt[b], c2 = cnt[128 + b];
    const int s1 = st[b], s2 = st[128 + b];
    const int nn = max(c1, c2);
    __shared__ float D2[256 * 32];
    __shared__ float redn[256], redx[256];
    const int tid = threadIdx.x;
    const int irow = tid & 63, jseg = tid >> 6;   // jseg uniform per wave
    const int i0 = it * 128 + irow, i1 = i0 + 64;
    const bool v0 = i0 < nn, v1 = i1 < nn;
    float r0[32], r1[32];
    {
        const float4* p0 = (const float4*)&af1[(size_t)(s1 + i0) * 32];
        const float4* p1 = (const float4*)&af1[(size_t)(s1 + i1) * 32];
#pragma unroll
        for (int q = 0; q < 8; ++q) {
            float4 a = (i0 < c1) ? p0[q] : make_float4(0, 0, 0, 0);
            float4 c = (i1 < c1) ? p1[q] : make_float4(0, 0, 0, 0);
            r0[q * 4] = a.x; r0[q * 4 + 1] = a.y; r0[q * 4 + 2] = a.z; r0[q * 4 + 3] = a.w;
            r1[q * 4] = c.x; r1[q * 4 + 1] = c.y; r1[q * 4 + 2] = c.z; r1[q * 4 + 3] = c.w;
        }
    }
    float lmn = 1e30f, lmx = -1e30f;
    for (int jh = 0; jh < 2; ++jh) {
        __syncthreads();
        for (int e = tid; e < 2048; e += 256) {
            int j = e >> 3, q4 = (e & 7) * 4;
            int jg = jh * 256 + j;
            float4 v = (jg < c2) ? *(const float4*)&af2[(size_t)(s2 + jg) * 32 + q4]
                                 : make_float4(0, 0, 0, 0);
            *(float4*)&D2[j * 32 + q4] = v;
        }
        __syncthreads();
        const int jbeg = jseg * 64;
        const int jend = min(jbeg + 64, nn - jh * 256);
        for (int j = jbeg; j < jend; ++j) {
            float a0 = 0, a1 = 0, a2 = 0, a3 = 0, b0 = 0, b1 = 0, b2 = 0, b3 = 0;
#pragma unroll
            for (int k = 0; k < 8; ++k) {
                float4 w = *(const float4*)&D2[j * 32 + k * 4];
                a0 += r0[k * 4] * w.x; a1 += r0[k * 4 + 1] * w.y;
                a2 += r0[k * 4 + 2] * w.z; a3 += r0[k * 4 + 3] * w.w;
                b0 += r1[k * 4] * w.x; b1 += r1[k * 4 + 1] * w.y;
                b2 += r1[k * 4 + 2] * w.z; b3 += r1[k * 4 + 3] * w.w;
            }
            float d0 = (a0 + a1) + (a2 + a3);
            float d1 = (b0 + b1) + (b2 + b3);
            if (v0) { lmn = fminf(lmn, d0); lmx = fmaxf(lmx, d0); }
            if (v1) { lmn = fminf(lmn, d1); lmx = fmaxf(lmx, d1); }
        }
    }
    redn[tid] = lmn; redx[tid] = lmx;
    __syncthreads();
    for (int sr = 128; sr; sr >>= 1) {
        if (tid < sr) {
            redn[tid] = fminf(redn[tid], redn[tid + sr]);
            redx[tid] = fmaxf(redx[tid], redx[tid + sr]);
        }
        __syncthreads();
    }
    if (tid == 0) { bmn[blockIdx.x] = redn[0]; bmx[blockIdx.x] = redx[0]; }
}

// ---------------- histogram pass 2: bin + accumulate ----------------
__global__ __launch_bounds__(256) void bin_k(const float* __restrict__ af1,
                                             const float* __restrict__ af2,
                                             const int* __restrict__ cnt, const int* __restrict__ st,
                                             const float* __restrict__ bmn, const float* __restrict__ bmx,
                                             float* __restrict__ hist) {
    const int b = blockIdx.x >> 2, it = blockIdx.x & 3;
    const int c1 = cnt[b], c2 = cnt[128 + b];
    const int s1 = st[b], s2 = st[128 + b];
    const int nn = max(c1, c2);
    __shared__ float D2[256 * 32];
    __shared__ int hloc[256 * 17];
    __shared__ int part[64];
    const int tid = threadIdx.x;
    const int irow = tid & 63, jseg = tid >> 6;
    const int i0 = it * 128 + irow, i1 = i0 + 64;
    const bool v0 = i0 < nn, v1 = i1 < nn;
    float dmn = 1e30f, dmx = -1e30f;
#pragma unroll
    for (int q = 0; q < 4; ++q) {
        dmn = fminf(dmn, bmn[(b << 2) + q]);
        dmx = fmaxf(dmx, bmx[(b << 2) + q]);
    }
    const float vMn = sigm(dmn), vMx = sigm(dmx);
    const float vScale = 16.f / ((vMx > vMn) ? (vMx - vMn) : 1.f);
    float r0[32], r1[32];
    {
        const float4* p0 = (const float4*)&af1[(size_t)(s1 + i0) * 32];
        const float4* p1 = (const float4*)&af1[(size_t)(s1 + i1) * 32];
#pragma unroll
        for (int q = 0; q < 8; ++q) {
            float4 a = (i0 < c1) ? p0[q] : make_float4(0, 0, 0, 0);
            float4 c = (i1 < c1) ? p1[q] : make_float4(0, 0, 0, 0);
            r0[q * 4] = a.x; r0[q * 4 + 1] = a.y; r0[q * 4 + 2] = a.z; r0[q * 4 + 3] = a.w;
            r1[q * 4] = c.x; r1[q * 4 + 1] = c.y; r1[q * 4 + 2] = c.z; r1[q * 4 + 3] = c.w;
        }
    }
#pragma unroll
    for (int q = 0; q < 17; ++q) hloc[tid * 17 + q] = 0;
    for (int jh = 0; jh < 2; ++jh) {
        __syncthreads();
        for (int e = tid; e < 2048; e += 256) {
            int j = e >> 3, q4 = (e & 7) * 4;
            int jg = jh * 256 + j;
            float4 v = (jg < c2) ? *(const float4*)&af2[(size_t)(s2 + jg) * 32 + q4]
                                 : make_float4(0, 0, 0, 0);
            *(float4*)&D2[j * 32 + q4] = v;
        }
        __syncthreads();
        const int jbeg = jseg * 64;
        const int jend = min(jbeg + 64, nn - jh * 256);
        for (int j = jbeg; j < jend; ++j) {
            float a0 = 0, a1 = 0, a2 = 0, a3 = 0, b0 = 0, b1 = 0, b2 = 0, b3 = 0;
#pragma unroll
            for (int k = 0; k < 8; ++k) {
                float4 w = *(const float4*)&D2[j * 32 + k * 4];
                a0 += r0[k * 4] * w.x; a1 += r0[k * 4 + 1] * w.y;
                a2 += r0[k * 4 + 2] * w.z; a3 += r0[k * 4 + 3] * w.w;
                b0 += r1[k * 4] * w.x; b1 += r1[k * 4 + 1] * w.y;
                b2 += r1[k * 4 + 2] * w.z; b3 += r1[k * 4 + 3] * w.w;
            }
            float d0 = (a0 + a1) + (a2 + a3);
            float d1 = (b0 + b1) + (b2 + b3);
            if (v0) {
                float t = (sigm(d0) - vMn) * vScale;
                int bi = (int)floorf(t);
                bi = bi < 0 ? 0 : (bi > 15 ? 15 : bi);
                hloc[tid * 17 + bi] += 1;
            }
            if (v1) {
                float t = (sigm(d1) - vMn) * vScale;
                int bi = (int)floorf(t);
                bi = bi < 0 ? 0 : (bi > 15 ? 15 : bi);
                hloc[tid * 17 + bi] += 1;
            }
        }
    }
    __syncthreads();
    if (tid < 64) {
        const int bin = tid & 15, q = tid >> 4;
        int s = 0;
        for (int t2 = q * 64; t2 < q * 64 + 64; ++t2) s += hloc[t2 * 17 + bin];
        part[tid] = s;
    }
    __syncthreads();
    if (tid < 16) {
        int s = part[tid] + part[16 + tid] + part[32 + tid] + part[48 + tid];
        atomicAdd(&hist[b * 16 + tid], (float)s);
    }
}

// ---------------- NTN + final MLP (one block per graph) ----------------
__global__ __launch_bounds__(64) void final_k(const float* __restrict__ pool, const float* __restrict__ hist,
                                              const int* __restrict__ cnt,
                                              const float* __restrict__ ntnW, const float* __restrict__ ntnV,
                                              const float* __restrict__ ntnb, const float* __restrict__ fc1W,
                                              const float* __restrict__ fc1b, const float* __restrict__ scW,
                                              const float* __restrict__ scb, float* __restrict__ out) {
    const int b = blockIdx.x;
    const int tid = threadIdx.x;
    __shared__ float P1[32], P2[32], feat[32], red[64];
    if (tid < 32) { P1[tid] = pool[b * 32 + tid]; P2[tid] = pool[4096 + b * 32 + tid]; }
    __syncthreads();
    const int k = tid & 15, part = tid >> 4;
    float acc = 0.f;
    for (int i = part * 8; i < part * 8 + 8; ++i) {
        float p1i = P1[i];
        for (int j = 0; j < 32; ++j) acc += p1i * P2[j] * ntnW[(i * 32 + j) * 16 + k];
    }
    red[tid] = acc;
    __syncthreads();
    if (tid < 16) {
        float bl = red[tid] + red[16 + tid] + red[32 + tid] + red[48 + tid];
        float blk = ntnb[tid];
        for (int i = 0; i < 32; ++i) blk += P1[i] * ntnV[tid * 64 + i];
        for (int j = 0; j < 32; ++j) blk += P2[j] * ntnV[tid * 64 + 32 + j];
        feat[tid] = fmaxf(bl + blk, 0.f);
        const int nn = max(cnt[b], cnt[128 + b]);
        feat[16 + tid] = hist[b * 16 + tid] / (float)(nn * nn);
    }
    __syncthreads();
    if (tid < 16) {
        float h = fc1b[tid];
        for (int f = 0; f < 32; ++f) h += feat[f] * fc1W[f * 16 + tid];
        red[tid] = fmaxf(h, 0.f);
    }
    __syncthreads();
    if (tid == 0) {
        float o = scb[0];
        for (int j = 0; j < 16; ++j) o += red[j] * scW[j];
        out[b] = 1.f / (1.f + expf(-o));
    }
}

// ---------------- launch ----------------
extern "C" void kernel_launch(void* const* d_in, const int* in_sizes, int n_in,
                              void* d_out, int out_size, void* d_ws, size_t ws_size,
                              hipStream_t stream) {
    const float* x1   = (const float*)d_in[0];
    const float* x2   = (const float*)d_in[1];
    const int*   ei1  = (const int*)d_in[2];
    const int*   ei2  = (const int*)d_in[3];
    const int*   bat1 = (const int*)d_in[4];
    const int*   bat2 = (const int*)d_in[5];
    const float* W1   = (const float*)d_in[6];
    const float* b1   = (const float*)d_in[7];
    const float* W2   = (const float*)d_in[8];
    const float* b2   = (const float*)d_in[9];
    const float* W3   = (const float*)d_in[10];
    const float* b3   = (const float*)d_in[11];
    const float* attW = (const float*)d_in[12];
    const float* ntnW = (const float*)d_in[13];
    const float* ntnV = (const float*)d_in[14];
    const float* ntnb = (const float*)d_in[15];
    const float* fc1W = (const float*)d_in[16];
    const float* fc1b = (const float*)d_in[17];
    const float* scW  = (const float*)d_in[18];
    const float* scb  = (const float*)d_in[19];
    float* out = (float*)d_out;

    // workspace layout (~85 MB)
    float* Hbuf   = (float*)d_ws;                        // 131072*64 f32
    float* Gbuf   = Hbuf + (size_t)TOT2 * 64;            // 131072*64 f32
    float* dis    = Gbuf + (size_t)TOT2 * 64;            // 131072
    int*   deg    = (int*)(dis + TOT2);                  // 131072
    int*   rowptr = deg + TOT2;                          // 131073
    int*   cursor = rowptr + TOT2 + 1;                   // 131072
    int*   csrs   = cursor + TOT2;                       // 2*1048576
    float* csrw   = (float*)(csrs + 2 * (size_t)Ec);     // 2*1048576
    int*   cnt    = (int*)(csrw + 2 * (size_t)Ec);       // 256
    int*   st     = cnt + 256;                           // 256
    float* pool   = (float*)(st + 256);                  // 8192
    float* hist   = pool + 8192;                         // 2048
    float* bmn    = hist + 2048;                         // 512
    float* bmx    = bmn + 512;                           // 512

    const int Eb = (int)(Ec / 256);                      // 4096 blocks over edges

    hipMemsetAsync(deg, 0, TOT2 * sizeof(int), stream);
    hipMemsetAsync(hist, 0, 2048 * sizeof(float), stream);
    degcnti_k<<<Eb, 256, 0, stream>>>(deg,       ei1 + Ec);   // dst = ei[1]
    degcnti_k<<<Eb, 256, 0, stream>>>(deg + TOT, ei2 + Ec);
    bs_k<<<1, 256, 0, stream>>>(bat1, bat2, cnt, st);
    dis_k<<<512, 256, 0, stream>>>(dis, deg);
    scan_side_k<<<2, 1024, 0, stream>>>(deg, rowptr);
    curcpy_k<<<512, 256, 0, stream>>>(rowptr, cursor);
    csrfill_k<<<Eb, 256, 0, stream>>>(ei1, ei1 + Ec, dis, cursor, csrs, csrw, 0);
    csrfill_k<<<Eb, 256, 0, stream>>>(ei2, ei2 + Ec, dis, cursor, csrs, csrw, TOT);

    // Layer 1 (K=128 -> 64)
    gemm_k<128, 64, false><<<256, 256, 0, stream>>>(x1, W1, Hbuf);
    gemm_k<128, 64, false><<<256, 256, 0, stream>>>(x2, W1, Hbuf + (size_t)TOT * 64);
    gather_k<64><<<TOT2 / 4, 256, 0, stream>>>(Gbuf, Hbuf, dis, b1, rowptr, csrs, csrw);

    // Layer 2 (64 -> 64), relu fused into GEMM load
    gemm_k<64, 64, true><<<512, 256, 0, stream>>>(Gbuf, W2, Hbuf);
    gather_k<64><<<TOT2 / 4, 256, 0, stream>>>(Gbuf, Hbuf, dis, b2, rowptr, csrs, csrw);

    // Layer 3 (64 -> 32)
    gemm_k<64, 32, true><<<512, 256, 0, stream>>>(Gbuf, W3, Hbuf);
    gather_k<32><<<TOT2 / 8, 256, 0, stream>>>(Gbuf, Hbuf, dis, b3, rowptr, csrs, csrw);

    // Pooling, histogram, head
    attpool_k<<<256, 256, 0, stream>>>(Gbuf, cnt, st, attW, pool);
    minmax_k<<<512, 256, 0, stream>>>(Gbuf, Gbuf + (size_t)TOT * 32, cnt, st, bmn, bmx);
    bin_k<<<512, 256, 0, stream>>>(Gbuf, Gbuf + (size_t)TOT * 32, cnt, st, bmn, bmx, hist);
    final_k<<<128, 64, 0, stream>>>(pool, hist, cnt, ntnW, ntnV, ntnb, fc1W, fc1b, scW, scb, out);
}

// Round 5
// 762.808 us; speedup vs baseline: 7.2645x; 1.1303x over previous
//
#include <hip/hip_runtime.h>
#include <hip/hip_bf16.h>

// Problem constants (fixed by setup_inputs)
constexpr int    TOT = 65536;        // nodes per side
constexpr int    TOT2 = 131072;      // both sides
constexpr int    F3c = 32;
constexpr long long Ec = 16LL * TOT; // 1048576 edges per side

typedef unsigned int   uint32;
typedef unsigned short ushort16;

__device__ __forceinline__ float sigm(float x) { return 1.f / (1.f + __expf(-x)); }

// f32 -> bf16 (round-to-nearest-even), returned in low 16 bits
__device__ __forceinline__ uint32 f2bf_rne(float x) {
    uint32 u = __float_as_uint(x);
    return (u + 0x7fffu + ((u >> 16) & 1u)) >> 16;
}
// unpack bf16x2 (low = even channel, high = odd channel)
__device__ __forceinline__ float2 bf2f(uint32 u) {
    return make_float2(__uint_as_float(u << 16), __uint_as_float(u & 0xffff0000u));
}

// ---------------- small utility kernels ----------------
__global__ void degcnti_k(int* __restrict__ deg, const int* __restrict__ dst) {
    int t = blockIdx.x * 256 + threadIdx.x;
    atomicAdd(&deg[dst[t]], 1);
}

__global__ void dis_k(float* __restrict__ dis, const int* __restrict__ deg) {
    int t = blockIdx.x * 256 + threadIdx.x;
    if (t < TOT2) dis[t] = rsqrtf((float)deg[t] + 1.0f);
}

// batch arrays are sorted: st/cnt per (side,graph) via binary search — no atomics.
__global__ void bs_k(const int* __restrict__ b1, const int* __restrict__ b2,
                     int* __restrict__ cnt, int* __restrict__ st) {
    int t = threadIdx.x;
    const int* bat = (t < 128) ? b1 : b2;
    const int g = t & 127;
    int lo = 0, hi = TOT;
    while (lo < hi) { int m = (lo + hi) >> 1; if (bat[m] < g) lo = m + 1; else hi = m; }
    const int s0 = lo;
    hi = TOT;
    while (lo < hi) { int m = (lo + hi) >> 1; if (bat[m] < g + 1) lo = m + 1; else hi = m; }
    st[t] = s0;
    cnt[t] = lo - s0;
}

// Exclusive scan of 65536 degrees per side -> global rowptr + cursor copy.
__global__ __launch_bounds__(1024) void scan_side_k(const int* __restrict__ deg, int* __restrict__ rowptr,
                                                    int* __restrict__ cursor) {
    const int side = blockIdx.x;
    const int* dg = deg + side * TOT;
    __shared__ int wsum[16];
    const int t = threadIdx.x, lane = t & 63, wid = t >> 6;
    const int base = t * 64;
    int run = 0;
    for (int q = 0; q < 64; ++q) run += dg[base + q];
    int inc = run;
#pragma unroll
    for (int d = 1; d < 64; d <<= 1) { int n = __shfl_up(inc, d, 64); if (lane >= d) inc += n; }
    if (lane == 63) wsum[wid] = inc;
    __syncthreads();
    if (t == 0) { int o = 0; for (int q = 0; q < 16; ++q) { int x = wsum[q]; wsum[q] = o; o += x; } }
    __syncthreads();
    int off = wsum[wid] + inc - run + side * (int)Ec;
    int* rp = rowptr + side * TOT;
    int* cp = cursor + side * TOT;
    for (int q = 0; q < 64; ++q) { int v = dg[base + q]; rp[base + q] = off; cp[base + q] = off; off += v; }
    if (side == 1 && t == 1023) rowptr[TOT2] = off;
}

__global__ void csrfill_k(const int* __restrict__ src, const int* __restrict__ dst,
                          const float* __restrict__ dis, int* __restrict__ cursor,
                          int* __restrict__ csr_src, float* __restrict__ csr_w, int base) {
    int e = blockIdx.x * 256 + threadIdx.x;
    int s = src[e] + base, d = dst[e] + base;
    int slot = atomicAdd(&cursor[d], 1);
    csr_src[slot] = s;
    csr_w[slot] = dis[s] * dis[d];
}

// ---------------- GEMM: out_bf16[M,NC] = (relu?)X[M,K] @ W[K,NC] ----------------
template<int K, int NC, bool RELU>
__global__ __launch_bounds__(256) void gemm_k(const float* __restrict__ X,
                                              const float* __restrict__ W,
                                              ushort16* __restrict__ out) {
    __shared__ float Ws[K * NC];
    const int tid = threadIdx.x;
    constexpr int WE4 = K * NC / 1024;
    {
        const float4* Wg = (const float4*)W;
        float4* Wp = (float4*)Ws;
#pragma unroll
        for (int it = 0; it < WE4; ++it) Wp[tid + it * 256] = Wg[tid + it * 256];
    }
    __syncthreads();
    const size_t row = (size_t)blockIdx.x * 256 + tid;
    const float4* Xr = (const float4*)(X + row * K);
    float acc[NC];
#pragma unroll
    for (int j = 0; j < NC; ++j) acc[j] = 0.f;
#pragma unroll 2
    for (int k4 = 0; k4 < K / 4; ++k4) {
        float4 xv = Xr[k4];
        if (RELU) {
            xv.x = fmaxf(xv.x, 0.f); xv.y = fmaxf(xv.y, 0.f);
            xv.z = fmaxf(xv.z, 0.f); xv.w = fmaxf(xv.w, 0.f);
        }
        const float xs[4] = {xv.x, xv.y, xv.z, xv.w};
#pragma unroll
        for (int kk = 0; kk < 4; ++kk) {
#pragma unroll
            for (int j4 = 0; j4 < NC / 4; ++j4) {
                float4 wv = *(const float4*)&Ws[(k4 * 4 + kk) * NC + j4 * 4];
                acc[j4 * 4 + 0] += xs[kk] * wv.x;
                acc[j4 * 4 + 1] += xs[kk] * wv.y;
                acc[j4 * 4 + 2] += xs[kk] * wv.z;
                acc[j4 * 4 + 3] += xs[kk] * wv.w;
            }
        }
    }
    uint4* O4 = (uint4*)(out + row * NC);
#pragma unroll
    for (int j8 = 0; j8 < NC / 8; ++j8) {
        uint4 v;
        v.x = f2bf_rne(acc[j8 * 8 + 0]) | (f2bf_rne(acc[j8 * 8 + 1]) << 16);
        v.y = f2bf_rne(acc[j8 * 8 + 2]) | (f2bf_rne(acc[j8 * 8 + 3]) << 16);
        v.z = f2bf_rne(acc[j8 * 8 + 4]) | (f2bf_rne(acc[j8 * 8 + 5]) << 16);
        v.w = f2bf_rne(acc[j8 * 8 + 6]) | (f2bf_rne(acc[j8 * 8 + 7]) << 16);
        O4[j8] = v;
    }
}

// ---------------- GCN aggregation: CSR gather over bf16 rows ----------------
// out_f32[i] = h[i]*dis[i]^2 + bias + sum_e h[csr_src[e]] * csr_w[e]
// One thread per bf16x2 channel pair: NC/2 threads per node.
template<int NC>
__global__ __launch_bounds__(256) void gather_k(float* __restrict__ out, const ushort16* __restrict__ h,
                                                const float* __restrict__ dis, const float* __restrict__ bias,
                                                const int* __restrict__ rowptr, const int* __restrict__ csr_src,
                                                const float* __restrict__ csr_w) {
    constexpr int TPN = NC / 2;            // threads per node
    constexpr int NPB = 256 / TPN;         // nodes per block
    const int tid = threadIdx.x;
    const int cp = tid & (TPN - 1);        // channel-pair index
    const int node = blockIdx.x * NPB + tid / TPN;
    const uint32* hrow = (const uint32*)h; // pair r*TPN + cp
    const float dv = dis[node];
    const float inv = dv * dv;
    const float2 bb = ((const float2*)bias)[cp];
    float2 sv = bf2f(hrow[(size_t)node * TPN + cp]);
    float acc0 = sv.x * inv + bb.x;
    float acc1 = sv.y * inv + bb.y;
    int e = rowptr[node];
    const int e1 = rowptr[node + 1];
    for (; e + 1 < e1; e += 2) {
        int s0 = csr_src[e], s1 = csr_src[e + 1];
        float w0 = csr_w[e], w1 = csr_w[e + 1];
        float2 f0 = bf2f(hrow[(size_t)s0 * TPN + cp]);
        float2 f1 = bf2f(hrow[(size_t)s1 * TPN + cp]);
        acc0 += f0.x * w0 + f1.x * w1;
        acc1 += f0.y * w0 + f1.y * w1;
    }
    if (e < e1) {
        float2 f0 = bf2f(hrow[(size_t)csr_src[e] * TPN + cp]);
        float w0 = csr_w[e];
        acc0 += f0.x * w0;
        acc1 += f0.y * w0;
    }
    *(float2*)&out[(size_t)node * NC + 2 * cp] = make_float2(acc0, acc1);
}

// ---------------- attention pooling (one block per (side,graph)) ----------------
__global__ __launch_bounds__(256) void attpool_k(const float* __restrict__ af,
                                                 const int* __restrict__ cnt, const int* __restrict__ st,
                                                 const float* __restrict__ attW, float* __restrict__ pool) {
    const int side = blockIdx.x >> 7, b = blockIdx.x & 127;
    const float* h = af + (size_t)side * TOT * F3c;
    const int c = cnt[side * 128 + b], s0 = st[side * 128 + b];
    const int f = threadIdx.x & 31, grp = threadIdx.x >> 5;
    __shared__ float red[8][32];
    __shared__ float mhS[32], tS[32];
    float acc = 0.f;
    for (int i = grp; i < c; i += 8) acc += h[(size_t)(s0 + i) * F3c + f];
    red[grp][f] = acc;
    __syncthreads();
    if (threadIdx.x < 32) { float tt = 0; for (int g = 0; g < 8; ++g) tt += red[g][f]; mhS[f] = tt / (float)c; }
    __syncthreads();
    if (threadIdx.x < 32) {
        float g = 0;
        for (int k = 0; k < 32; ++k) g += mhS[k] * attW[k * 32 + f];
        tS[f] = tanhf(g);
    }
    __syncthreads();
    const float tf = tS[f];
    acc = 0.f;
    for (int i = grp; i < c; i += 8) {
        float hv = h[(size_t)(s0 + i) * F3c + f];
        float pr = hv * tf;
#pragma unroll
        for (int m = 16; m; m >>= 1) pr += __shfl_xor(pr, m, 32);
        float sA = 1.f / (1.f + expf(-pr));
        acc += hv * sA;
    }
    __syncthreads();
    red[grp][f] = acc;
    __syncthreads();
    if (threadIdx.x < 32) {
        float tt = 0; for (int g = 0; g < 8; ++g) tt += red[g][f];
        pool[(size_t)(side * 128 + b) * 32 + f] = tt;
    }
}

// ---------------- histogram pass 1: per-(graph, i-tile) raw-dot min/max ----------------
__global__ __launch_bounds__(256) void minmax_k(const float* __restrict__ af1,
                                                const float* __restrict__ af2,
                                                const int* __restrict__ cnt, const int* __restrict__ st,
                                                float* __restrict__ bmn, float* __restrict__ bmx) {
    const int b = blockIdx.x >> 2, it = blockIdx.x & 3;
    const int c1 = cnt[b], c2 = cnt[128 + b];
    const int s1 = st[b], s2 = st[128 + b];
    const int nn = max(c1, c2);
    __shared__ float D2[256 * 32];
    __shared__ float redn[256], redx[256];
    const int tid = threadIdx.x;
    const int irow = tid & 63, jseg = tid >> 6;
    const int i0 = it * 128 + irow, i1 = i0 + 64;
    const bool v0 = i0 < nn, v1 = i1 < nn;
    float r0[32], r1[32];
    {
        const float4* p0 = (const float4*)&af1[(size_t)(s1 + i0) * 32];
        const float4* p1 = (const float4*)&af1[(size_t)(s1 + i1) * 32];
#pragma unroll
        for (int q = 0; q < 8; ++q) {
            float4 a = (i0 < c1) ? p0[q] : make_float4(0, 0, 0, 0);
            float4 c = (i1 < c1) ? p1[q] : make_float4(0, 0, 0, 0);
            r0[q * 4] = a.x; r0[q * 4 + 1] = a.y; r0[q * 4 + 2] = a.z; r0[q * 4 + 3] = a.w;
            r1[q * 4] = c.x; r1[q * 4 + 1] = c.y; r1[q * 4 + 2] = c.z; r1[q * 4 + 3] = c.w;
        }
    }
    float lmn = 1e30f, lmx = -1e30f;
    for (int jh = 0; jh < 2; ++jh) {
        __syncthreads();
        for (int e = tid; e < 2048; e += 256) {
            int j = e >> 3, q4 = (e & 7) * 4;
            int jg = jh * 256 + j;
            float4 v = (jg < c2) ? *(const float4*)&af2[(size_t)(s2 + jg) * 32 + q4]
                                 : make_float4(0, 0, 0, 0);
            *(float4*)&D2[j * 32 + q4] = v;
        }
        __syncthreads();
        const int jbeg = jseg * 64;
        const int jend = min(jbeg + 64, nn - jh * 256);
        for (int j = jbeg; j < jend; ++j) {
            float a0 = 0, a1 = 0, a2 = 0, a3 = 0, b0 = 0, b1 = 0, b2 = 0, b3 = 0;
#pragma unroll
            for (int k = 0; k < 8; ++k) {
                float4 w = *(const float4*)&D2[j * 32 + k * 4];
                a0 += r0[k * 4] * w.x; a1 += r0[k * 4 + 1] * w.y;
                a2 += r0[k * 4 + 2] * w.z; a3 += r0[k * 4 + 3] * w.w;
                b0 += r1[k * 4] * w.x; b1 += r1[k * 4 + 1] * w.y;
                b2 += r1[k * 4 + 2] * w.z; b3 += r1[k * 4 + 3] * w.w;
            }
            float d0 = (a0 + a1) + (a2 + a3);
            float d1 = (b0 + b1) + (b2 + b3);
            if (v0) { lmn = fminf(lmn, d0); lmx = fmaxf(lmx, d0); }
            if (v1) { lmn = fminf(lmn, d1); lmx = fmaxf(lmx, d1); }
        }
    }
    redn[tid] = lmn; redx[tid] = lmx;
    __syncthreads();
    for (int sr = 128; sr; sr >>= 1) {
        if (tid < sr) {
            redn[tid] = fminf(redn[tid], redn[tid + sr]);
            redx[tid] = fmaxf(redx[tid], redx[tid + sr]);
        }
        __syncthreads();
    }
    if (tid == 0) { bmn[blockIdx.x] = redn[0]; bmx[blockIdx.x] = redx[0]; }
}

// ---------------- histogram pass 2: bin + accumulate ----------------
__global__ __launch_bounds__(256) void bin_k(const float* __restrict__ af1,
                                             const float* __restrict__ af2,
                                             const int* __restrict__ cnt, const int* __restrict__ st,
                                             const float* __restrict__ bmn, const float* __restrict__ bmx,
                                             float* __restrict__ hist) {
    const int b = blockIdx.x >> 2, it = blockIdx.x & 3;
    const int c1 = cnt[b], c2 = cnt[128 + b];
    const int s1 = st[b], s2 = st[128 + b];
    const int nn = max(c1, c2);
    __shared__ float D2[256 * 32];
    __shared__ int hloc[256 * 17];
    __shared__ int part[64];
    const int tid = threadIdx.x;
    const int irow = tid & 63, jseg = tid >> 6;
    const int i0 = it * 128 + irow, i1 = i0 + 64;
    const bool v0 = i0 < nn, v1 = i1 < nn;
    float dmn = 1e30f, dmx = -1e30f;
#pragma unroll
    for (int q = 0; q < 4; ++q) {
        dmn = fminf(dmn, bmn[(b << 2) + q]);
        dmx = fmaxf(dmx, bmx[(b << 2) + q]);
    }
    const float vMn = sigm(dmn), vMx = sigm(dmx);
    const float vScale = 16.f / ((vMx > vMn) ? (vMx - vMn) : 1.f);
    float r0[32], r1[32];
    {
        const float4* p0 = (const float4*)&af1[(size_t)(s1 + i0) * 32];
        const float4* p1 = (const float4*)&af1[(size_t)(s1 + i1) * 32];
#pragma unroll
        for (int q = 0; q < 8; ++q) {
            float4 a = (i0 < c1) ? p0[q] : make_float4(0, 0, 0, 0);
            float4 c = (i1 < c1) ? p1[q] : make_float4(0, 0, 0, 0);
            r0[q * 4] = a.x; r0[q * 4 + 1] = a.y; r0[q * 4 + 2] = a.z; r0[q * 4 + 3] = a.w;
            r1[q * 4] = c.x; r1[q * 4 + 1] = c.y; r1[q * 4 + 2] = c.z; r1[q * 4 + 3] = c.w;
        }
    }
#pragma unroll
    for (int q = 0; q < 17; ++q) hloc[tid * 17 + q] = 0;
    for (int jh = 0; jh < 2; ++jh) {
        __syncthreads();
        for (int e = tid; e < 2048; e += 256) {
            int j = e >> 3, q4 = (e & 7) * 4;
            int jg = jh * 256 + j;
            float4 v = (jg < c2) ? *(const float4*)&af2[(size_t)(s2 + jg) * 32 + q4]
                                 : make_float4(0, 0, 0, 0);
            *(float4*)&D2[j * 32 + q4] = v;
        }
        __syncthreads();
        const int jbeg = jseg * 64;
        const int jend = min(jbeg + 64, nn - jh * 256);
        for (int j = jbeg; j < jend; ++j) {
            float a0 = 0, a1 = 0, a2 = 0, a3 = 0, b0 = 0, b1 = 0, b2 = 0, b3 = 0;
#pragma unroll
            for (int k = 0; k < 8; ++k) {
                float4 w = *(const float4*)&D2[j * 32 + k * 4];
                a0 += r0[k * 4] * w.x; a1 += r0[k * 4 + 1] * w.y;
                a2 += r0[k * 4 + 2] * w.z; a3 += r0[k * 4 + 3] * w.w;
                b0 += r1[k * 4] * w.x; b1 += r1[k * 4 + 1] * w.y;
                b2 += r1[k * 4 + 2] * w.z; b3 += r1[k * 4 + 3] * w.w;
            }
            float d0 = (a0 + a1) + (a2 + a3);
            float d1 = (b0 + b1) + (b2 + b3);
            if (v0) {
                float t = (sigm(d0) - vMn) * vScale;
                int bi = (int)floorf(t);
                bi = bi < 0 ? 0 : (bi > 15 ? 15 : bi);
                hloc[tid * 17 + bi] += 1;
            }
            if (v1) {
                float t = (sigm(d1) - vMn) * vScale;
                int bi = (int)floorf(t);
                bi = bi < 0 ? 0 : (bi > 15 ? 15 : bi);
                hloc[tid * 17 + bi] += 1;
            }
        }
    }
    __syncthreads();
    if (tid < 64) {
        const int bin = tid & 15, q = tid >> 4;
        int s = 0;
        for (int t2 = q * 64; t2 < q * 64 + 64; ++t2) s += hloc[t2 * 17 + bin];
        part[tid] = s;
    }
    __syncthreads();
    if (tid < 16) {
        int s = part[tid] + part[16 + tid] + part[32 + tid] + part[48 + tid];
        atomicAdd(&hist[b * 16 + tid], (float)s);
    }
}

// ---------------- NTN + final MLP (one block per graph) ----------------
__global__ __launch_bounds__(64) void final_k(const float* __restrict__ pool, const float* __restrict__ hist,
                                              const int* __restrict__ cnt,
                                              const float* __restrict__ ntnW, const float* __restrict__ ntnV,
                                              const float* __restrict__ ntnb, const float* __restrict__ fc1W,
                                              const float* __restrict__ fc1b, const float* __restrict__ scW,
                                              const float* __restrict__ scb, float* __restrict__ out) {
    const int b = blockIdx.x;
    const int tid = threadIdx.x;
    __shared__ float P1[32], P2[32], feat[32], red[64];
    if (tid < 32) { P1[tid] = pool[b * 32 + tid]; P2[tid] = pool[4096 + b * 32 + tid]; }
    __syncthreads();
    const int k = tid & 15, part = tid >> 4;
    float acc = 0.f;
    for (int i = part * 8; i < part * 8 + 8; ++i) {
        float p1i = P1[i];
        for (int j = 0; j < 32; ++j) acc += p1i * P2[j] * ntnW[(i * 32 + j) * 16 + k];
    }
    red[tid] = acc;
    __syncthreads();
    if (tid < 16) {
        float bl = red[tid] + red[16 + tid] + red[32 + tid] + red[48 + tid];
        float blk = ntnb[tid];
        for (int i = 0; i < 32; ++i) blk += P1[i] * ntnV[tid * 64 + i];
        for (int j = 0; j < 32; ++j) blk += P2[j] * ntnV[tid * 64 + 32 + j];
        feat[tid] = fmaxf(bl + blk, 0.f);
        const int nn = max(cnt[b], cnt[128 + b]);
        feat[16 + tid] = hist[b * 16 + tid] / (float)(nn * nn);
    }
    __syncthreads();
    if (tid < 16) {
        float h = fc1b[tid];
        for (int f = 0; f < 32; ++f) h += feat[f] * fc1W[f * 16 + tid];
        red[tid] = fmaxf(h, 0.f);
    }
    __syncthreads();
    if (tid == 0) {
        float o = scb[0];
        for (int j = 0; j < 16; ++j) o += red[j] * scW[j];
        out[b] = 1.f / (1.f + expf(-o));
    }
}

// ---------------- launch ----------------
extern "C" void kernel_launch(void* const* d_in, const int* in_sizes, int n_in,
                              void* d_out, int out_size, void* d_ws, size_t ws_size,
                              hipStream_t stream) {
    const float* x1   = (const float*)d_in[0];
    const float* x2   = (const float*)d_in[1];
    const int*   ei1  = (const int*)d_in[2];
    const int*   ei2  = (const int*)d_in[3];
    const int*   bat1 = (const int*)d_in[4];
    const int*   bat2 = (const int*)d_in[5];
    const float* W1   = (const float*)d_in[6];
    const float* b1   = (const float*)d_in[7];
    const float* W2   = (const float*)d_in[8];
    const float* b2   = (const float*)d_in[9];
    const float* W3   = (const float*)d_in[10];
    const float* b3   = (const float*)d_in[11];
    const float* attW = (const float*)d_in[12];
    const float* ntnW = (const float*)d_in[13];
    const float* ntnV = (const float*)d_in[14];
    const float* ntnb = (const float*)d_in[15];
    const float* fc1W = (const float*)d_in[16];
    const float* fc1b = (const float*)d_in[17];
    const float* scW  = (const float*)d_in[18];
    const float* scb  = (const float*)d_in[19];
    float* out = (float*)d_out;

    // workspace layout (~70 MB)
    ushort16* Hbuf = (ushort16*)d_ws;                    // 131072*64 bf16 (16.8 MB)
    float* Gbuf   = (float*)(Hbuf + (size_t)TOT2 * 64);  // 131072*64 f32  (33.5 MB)
    float* dis    = Gbuf + (size_t)TOT2 * 64;            // 131072
    int*   deg    = (int*)(dis + TOT2);                  // 131072
    int*   rowptr = deg + TOT2;                          // 131073
    int*   cursor = rowptr + TOT2 + 1;                   // 131072
    int*   csrs   = cursor + TOT2;                       // 2*1048576
    float* csrw   = (float*)(csrs + 2 * (size_t)Ec);     // 2*1048576
    int*   cnt    = (int*)(csrw + 2 * (size_t)Ec);       // 256
    int*   st     = cnt + 256;                           // 256
    float* pool   = (float*)(st + 256);                  // 8192
    float* hist   = pool + 8192;                         // 2048
    float* bmn    = hist + 2048;                         // 512
    float* bmx    = bmn + 512;                           // 512

    const int Eb = (int)(Ec / 256);                      // 4096 blocks over edges

    hipMemsetAsync(deg, 0, TOT2 * sizeof(int), stream);
    hipMemsetAsync(hist, 0, 2048 * sizeof(float), stream);
    degcnti_k<<<Eb, 256, 0, stream>>>(deg,       ei1 + Ec);   // dst = ei[1]
    degcnti_k<<<Eb, 256, 0, stream>>>(deg + TOT, ei2 + Ec);
    bs_k<<<1, 256, 0, stream>>>(bat1, bat2, cnt, st);
    dis_k<<<512, 256, 0, stream>>>(dis, deg);
    scan_side_k<<<2, 1024, 0, stream>>>(deg, rowptr, cursor);
    csrfill_k<<<Eb, 256, 0, stream>>>(ei1, ei1 + Ec, dis, cursor, csrs, csrw, 0);
    csrfill_k<<<Eb, 256, 0, stream>>>(ei2, ei2 + Ec, dis, cursor, csrs, csrw, TOT);

    // Layer 1 (K=128 -> 64)
    gemm_k<128, 64, false><<<256, 256, 0, stream>>>(x1, W1, Hbuf);
    gemm_k<128, 64, false><<<256, 256, 0, stream>>>(x2, W1, Hbuf + (size_t)TOT * 64);
    gather_k<64><<<TOT2 / 8, 256, 0, stream>>>(Gbuf, Hbuf, dis, b1, rowptr, csrs, csrw);

    // Layer 2 (64 -> 64), relu fused into GEMM load
    gemm_k<64, 64, true><<<512, 256, 0, stream>>>(Gbuf, W2, Hbuf);
    gather_k<64><<<TOT2 / 8, 256, 0, stream>>>(Gbuf, Hbuf, dis, b2, rowptr, csrs, csrw);

    // Layer 3 (64 -> 32)
    gemm_k<64, 32, true><<<512, 256, 0, stream>>>(Gbuf, W3, Hbuf);
    gather_k<32><<<TOT2 / 16, 256, 0, stream>>>(Gbuf, Hbuf, dis, b3, rowptr, csrs, csrw);

    // Pooling, histogram, head
    attpool_k<<<256, 256, 0, stream>>>(Gbuf, cnt, st, attW, pool);
    minmax_k<<<512, 256, 0, stream>>>(Gbuf, Gbuf + (size_t)TOT * 32, cnt, st, bmn, bmx);
    bin_k<<<512, 256, 0, stream>>>(Gbuf, Gbuf + (size_t)TOT * 32, cnt, st, bmn, bmx, hist);
    final_k<<<128, 64, 0, stream>>>(pool, hist, cnt, ntnW, ntnV, ntnb, fc1W, fc1b, scW, scb, out);
}

// Round 6
// 663.430 us; speedup vs baseline: 8.3527x; 1.1498x over previous
//
#include <hip/hip_runtime.h>
#include <hip/hip_bf16.h>

// Problem constants (fixed by setup_inputs)
constexpr int    TOT = 65536;        // nodes per side
constexpr int    TOT2 = 131072;      // both sides
constexpr long long Ec = 16LL * TOT; // 1048576 edges per side

typedef unsigned int   uint32;
typedef unsigned short ushort16;
typedef __attribute__((ext_vector_type(8))) short bf16x8;
typedef __attribute__((ext_vector_type(4))) float f32x4;

__device__ __forceinline__ float sigm(float x) { return 1.f / (1.f + __expf(-x)); }

// f32 -> bf16 (round-to-nearest-even), low 16 bits
__device__ __forceinline__ uint32 f2bf_rne(float x) {
    uint32 u = __float_as_uint(x);
    return (u + 0x7fffu + ((u >> 16) & 1u)) >> 16;
}
__device__ __forceinline__ float2 bf2f(uint32 u) {
    return make_float2(__uint_as_float(u << 16), __uint_as_float(u & 0xffff0000u));
}
__device__ __forceinline__ float bf1f(ushort16 u) {
    return __uint_as_float(((uint32)u) << 16);
}

// ---------------- small utility kernels ----------------
// both sides in one dispatch: t in [0, 2*Ec)
__global__ void degcnt2_k(int* __restrict__ deg, const int* __restrict__ dst1,
                          const int* __restrict__ dst2) {
    long long t = (long long)blockIdx.x * 256 + threadIdx.x;
    if (t < Ec) atomicAdd(&deg[dst1[t]], 1);
    else        atomicAdd(&deg[TOT + dst2[t - Ec]], 1);
}

__global__ void dis_k(float* __restrict__ dis, const int* __restrict__ deg) {
    int t = blockIdx.x * 256 + threadIdx.x;
    if (t < TOT2) dis[t] = rsqrtf((float)deg[t] + 1.0f);
}

// batch arrays sorted: st/cnt per (side,graph) via binary search
__global__ void bs_k(const int* __restrict__ b1, const int* __restrict__ b2,
                     int* __restrict__ cnt, int* __restrict__ st) {
    int t = threadIdx.x;
    const int* bat = (t < 128) ? b1 : b2;
    const int g = t & 127;
    int lo = 0, hi = TOT;
    while (lo < hi) { int m = (lo + hi) >> 1; if (bat[m] < g) lo = m + 1; else hi = m; }
    const int s0 = lo;
    hi = TOT;
    while (lo < hi) { int m = (lo + hi) >> 1; if (bat[m] < g + 1) lo = m + 1; else hi = m; }
    st[t] = s0;
    cnt[t] = lo - s0;
}

// Exclusive scan of degrees per side -> global rowptr + cursor copy.
__global__ __launch_bounds__(1024) void scan_side_k(const int* __restrict__ deg, int* __restrict__ rowptr,
                                                    int* __restrict__ cursor) {
    const int side = blockIdx.x;
    const int* dg = deg + side * TOT;
    __shared__ int wsum[16];
    const int t = threadIdx.x, lane = t & 63, wid = t >> 6;
    const int base = t * 64;
    int run = 0;
    for (int q = 0; q < 64; ++q) run += dg[base + q];
    int inc = run;
#pragma unroll
    for (int d = 1; d < 64; d <<= 1) { int n = __shfl_up(inc, d, 64); if (lane >= d) inc += n; }
    if (lane == 63) wsum[wid] = inc;
    __syncthreads();
    if (t == 0) { int o = 0; for (int q = 0; q < 16; ++q) { int x = wsum[q]; wsum[q] = o; o += x; } }
    __syncthreads();
    int off = wsum[wid] + inc - run + side * (int)Ec;
    int* rp = rowptr + side * TOT;
    int* cp = cursor + side * TOT;
    for (int q = 0; q < 64; ++q) { int v = dg[base + q]; rp[base + q] = off; cp[base + q] = off; off += v; }
    if (side == 1 && t == 1023) rowptr[TOT2] = off;
}

// both sides in one dispatch
__global__ void csrfill2_k(const int* __restrict__ ei1, const int* __restrict__ ei2,
                           const float* __restrict__ dis, int* __restrict__ cursor,
                           int* __restrict__ csr_src, float* __restrict__ csr_w) {
    long long t = (long long)blockIdx.x * 256 + threadIdx.x;
    int s, d;
    if (t < Ec) { s = ei1[t];      d = ei1[Ec + t]; }
    else        { s = ei2[t - Ec] + TOT; d = ei2[Ec + t - Ec] + TOT; }
    int slot = atomicAdd(&cursor[d], 1);
    csr_src[slot] = s;
    csr_w[slot] = dis[s] * dis[d];
}

// ---------------- GEMM: out_bf16[M,NC] = (relu?)X[M,K] @ W[K,NC] ----------------
template<int K, int NC, bool RELU>
__global__ __launch_bounds__(256) void gemm_k(const float* __restrict__ X1,
                                              const float* __restrict__ X2,   // may equal X1 (contiguous)
                                              const float* __restrict__ W,
                                              ushort16* __restrict__ out) {
    __shared__ float Ws[K * NC];
    const int tid = threadIdx.x;
    constexpr int WE4 = K * NC / 1024;
    {
        const float4* Wg = (const float4*)W;
        float4* Wp = (float4*)Ws;
#pragma unroll
        for (int it = 0; it < WE4; ++it) Wp[tid + it * 256] = Wg[tid + it * 256];
    }
    __syncthreads();
    const size_t row = (size_t)blockIdx.x * 256 + tid;
    const float4* Xr = (row < TOT) ? (const float4*)(X1 + row * K)
                                   : (const float4*)(X2 + (row - TOT) * K);
    float acc[NC];
#pragma unroll
    for (int j = 0; j < NC; ++j) acc[j] = 0.f;
#pragma unroll 2
    for (int k4 = 0; k4 < K / 4; ++k4) {
        float4 xv = Xr[k4];
        if (RELU) {
            xv.x = fmaxf(xv.x, 0.f); xv.y = fmaxf(xv.y, 0.f);
            xv.z = fmaxf(xv.z, 0.f); xv.w = fmaxf(xv.w, 0.f);
        }
        const float xs[4] = {xv.x, xv.y, xv.z, xv.w};
#pragma unroll
        for (int kk = 0; kk < 4; ++kk) {
#pragma unroll
            for (int j4 = 0; j4 < NC / 4; ++j4) {
                float4 wv = *(const float4*)&Ws[(k4 * 4 + kk) * NC + j4 * 4];
                acc[j4 * 4 + 0] += xs[kk] * wv.x;
                acc[j4 * 4 + 1] += xs[kk] * wv.y;
                acc[j4 * 4 + 2] += xs[kk] * wv.z;
                acc[j4 * 4 + 3] += xs[kk] * wv.w;
            }
        }
    }
    uint4* O4 = (uint4*)(out + row * NC);
#pragma unroll
    for (int j8 = 0; j8 < NC / 8; ++j8) {
        uint4 v;
        v.x = f2bf_rne(acc[j8 * 8 + 0]) | (f2bf_rne(acc[j8 * 8 + 1]) << 16);
        v.y = f2bf_rne(acc[j8 * 8 + 2]) | (f2bf_rne(acc[j8 * 8 + 3]) << 16);
        v.z = f2bf_rne(acc[j8 * 8 + 4]) | (f2bf_rne(acc[j8 * 8 + 5]) << 16);
        v.w = f2bf_rne(acc[j8 * 8 + 6]) | (f2bf_rne(acc[j8 * 8 + 7]) << 16);
        O4[j8] = v;
    }
}

// ---------------- GCN aggregation: CSR gather over bf16 rows, f32 out ----------------
template<int NC>
__global__ __launch_bounds__(256) void gather_k(float* __restrict__ out, const ushort16* __restrict__ h,
                                                const float* __restrict__ dis, const float* __restrict__ bias,
                                                const int* __restrict__ rowptr, const int* __restrict__ csr_src,
                                                const float* __restrict__ csr_w) {
    constexpr int TPN = NC / 2;
    constexpr int NPB = 256 / TPN;
    const int tid = threadIdx.x;
    const int cp = tid & (TPN - 1);
    const int node = blockIdx.x * NPB + tid / TPN;
    const uint32* hrow = (const uint32*)h;
    const float dv = dis[node];
    const float inv = dv * dv;
    const float2 bb = ((const float2*)bias)[cp];
    float2 sv = bf2f(hrow[(size_t)node * TPN + cp]);
    float acc0 = sv.x * inv + bb.x;
    float acc1 = sv.y * inv + bb.y;
    int e = rowptr[node];
    const int e1 = rowptr[node + 1];
    for (; e + 1 < e1; e += 2) {
        int s0 = csr_src[e], s1 = csr_src[e + 1];
        float w0 = csr_w[e], w1 = csr_w[e + 1];
        float2 f0 = bf2f(hrow[(size_t)s0 * TPN + cp]);
        float2 f1 = bf2f(hrow[(size_t)s1 * TPN + cp]);
        acc0 += f0.x * w0 + f1.x * w1;
        acc1 += f0.y * w0 + f1.y * w1;
    }
    if (e < e1) {
        float2 f0 = bf2f(hrow[(size_t)csr_src[e] * TPN + cp]);
        float w0 = csr_w[e];
        acc0 += f0.x * w0;
        acc1 += f0.y * w0;
    }
    *(float2*)&out[(size_t)node * NC + 2 * cp] = make_float2(acc0, acc1);
}

// Layer-3 gather: bf16 output rows (32 channels)
__global__ __launch_bounds__(256) void gather32b_k(uint32* __restrict__ out, const ushort16* __restrict__ h,
                                                   const float* __restrict__ dis, const float* __restrict__ bias,
                                                   const int* __restrict__ rowptr, const int* __restrict__ csr_src,
                                                   const float* __restrict__ csr_w) {
    constexpr int TPN = 16;
    const int tid = threadIdx.x;
    const int cp = tid & 15;
    const int node = blockIdx.x * 16 + tid / TPN;
    const uint32* hrow = (const uint32*)h;
    const float dv = dis[node];
    const float inv = dv * dv;
    const float2 bb = ((const float2*)bias)[cp];
    float2 sv = bf2f(hrow[(size_t)node * TPN + cp]);
    float acc0 = sv.x * inv + bb.x;
    float acc1 = sv.y * inv + bb.y;
    int e = rowptr[node];
    const int e1 = rowptr[node + 1];
    for (; e + 1 < e1; e += 2) {
        int s0 = csr_src[e], s1 = csr_src[e + 1];
        float w0 = csr_w[e], w1 = csr_w[e + 1];
        float2 f0 = bf2f(hrow[(size_t)s0 * TPN + cp]);
        float2 f1 = bf2f(hrow[(size_t)s1 * TPN + cp]);
        acc0 += f0.x * w0 + f1.x * w1;
        acc1 += f0.y * w0 + f1.y * w1;
    }
    if (e < e1) {
        float2 f0 = bf2f(hrow[(size_t)csr_src[e] * TPN + cp]);
        float w0 = csr_w[e];
        acc0 += f0.x * w0;
        acc1 += f0.y * w0;
    }
    out[(size_t)node * 16 + cp] = f2bf_rne(acc0) | (f2bf_rne(acc1) << 16);
}

// ---------------- attention pooling (bf16 AF input) ----------------
__global__ __launch_bounds__(256) void attpool_k(const ushort16* __restrict__ af,
                                                 const int* __restrict__ cnt, const int* __restrict__ st,
                                                 const float* __restrict__ attW, float* __restrict__ pool) {
    const int side = blockIdx.x >> 7, b = blockIdx.x & 127;
    const ushort16* h = af + (size_t)side * TOT * 32;
    const int c = cnt[side * 128 + b], s0 = st[side * 128 + b];
    const int f = threadIdx.x & 31, grp = threadIdx.x >> 5;
    __shared__ float red[8][32];
    __shared__ float mhS[32], tS[32];
    float acc = 0.f;
    for (int i = grp; i < c; i += 8) acc += bf1f(h[(size_t)(s0 + i) * 32 + f]);
    red[grp][f] = acc;
    __syncthreads();
    if (threadIdx.x < 32) { float tt = 0; for (int g = 0; g < 8; ++g) tt += red[g][f]; mhS[f] = tt / (float)c; }
    __syncthreads();
    if (threadIdx.x < 32) {
        float g = 0;
        for (int k = 0; k < 32; ++k) g += mhS[k] * attW[k * 32 + f];
        tS[f] = tanhf(g);
    }
    __syncthreads();
    const float tf = tS[f];
    acc = 0.f;
    for (int i = grp; i < c; i += 8) {
        float hv = bf1f(h[(size_t)(s0 + i) * 32 + f]);
        float pr = hv * tf;
#pragma unroll
        for (int m = 16; m; m >>= 1) pr += __shfl_xor(pr, m, 32);
        float sA = 1.f / (1.f + expf(-pr));
        acc += hv * sA;
    }
    __syncthreads();
    red[grp][f] = acc;
    __syncthreads();
    if (threadIdx.x < 32) {
        float tt = 0; for (int g = 0; g < 8; ++g) tt += red[g][f];
        pool[(size_t)(side * 128 + b) * 32 + f] = tt;
    }
}

// ---------------- histogram pass 1: MFMA min/max of raw dots ----------------
// grid = 128 graphs * 8; per wave: 1 i-tile (16 rows) x all j-tiles. S = AF1 @ AF2^T.
__global__ __launch_bounds__(256) void mm2_k(const ushort16* __restrict__ afb,
                                             const int* __restrict__ cnt, const int* __restrict__ st,
                                             float* __restrict__ bmn, float* __restrict__ bmx) {
    const int b = blockIdx.x >> 3, it8 = blockIdx.x & 7;
    const int c1 = cnt[b], c2 = cnt[128 + b];
    const int s1 = st[b], s2 = st[128 + b];
    const int nn = max(c1, c2);
    const int tid = threadIdx.x, lane = tid & 63, wave = tid >> 6;
    const int itile = it8 * 4 + wave;
    const int i0 = itile * 16;
    float lmn = 1e30f, lmx = -1e30f;
    if (i0 < nn) {
        const int arow = i0 + (lane & 15);
        const int koff = (lane >> 4) * 8;
        bf16x8 a = {0, 0, 0, 0, 0, 0, 0, 0};
        if (arow < c1) a = *(const bf16x8*)(afb + (size_t)(s1 + arow) * 32 + koff);
        const int ibase = i0 + (lane >> 4) * 4;
        const int njt = (nn + 15) >> 4;
        for (int jt = 0; jt < njt; ++jt) {
            const int brow = jt * 16 + (lane & 15);
            bf16x8 bb = {0, 0, 0, 0, 0, 0, 0, 0};
            if (brow < c2) bb = *(const bf16x8*)(afb + (size_t)(s2 + brow) * 32 + koff);
            f32x4 cc = {0.f, 0.f, 0.f, 0.f};
            cc = __builtin_amdgcn_mfma_f32_16x16x32_bf16(a, bb, cc, 0, 0, 0);
            if (brow < nn) {
#pragma unroll
                for (int r = 0; r < 4; ++r) {
                    if (ibase + r < nn) { lmn = fminf(lmn, cc[r]); lmx = fmaxf(lmx, cc[r]); }
                }
            }
        }
    }
    __shared__ float redn[256], redx[256];
    redn[tid] = lmn; redx[tid] = lmx;
    __syncthreads();
    for (int sr = 128; sr; sr >>= 1) {
        if (tid < sr) {
            redn[tid] = fminf(redn[tid], redn[tid + sr]);
            redx[tid] = fmaxf(redx[tid], redx[tid + sr]);
        }
        __syncthreads();
    }
    if (tid == 0) { bmn[blockIdx.x] = redn[0]; bmx[blockIdx.x] = redx[0]; }
}

// ---------------- histogram pass 2: MFMA + bin ----------------
__global__ __launch_bounds__(256) void bin2_k(const ushort16* __restrict__ afb,
                                              const int* __restrict__ cnt, const int* __restrict__ st,
                                              const float* __restrict__ bmn, const float* __restrict__ bmx,
                                              float* __restrict__ hist) {
    const int b = blockIdx.x >> 3, it8 = blockIdx.x & 7;
    const int c1 = cnt[b], c2 = cnt[128 + b];
    const int s1 = st[b], s2 = st[128 + b];
    const int nn = max(c1, c2);
    const int tid = threadIdx.x, lane = tid & 63, wave = tid >> 6;
    const int itile = it8 * 4 + wave;
    const int i0 = itile * 16;
    float dmn = 1e30f, dmx = -1e30f;
#pragma unroll
    for (int q = 0; q < 8; ++q) {
        dmn = fminf(dmn, bmn[(b << 3) + q]);
        dmx = fmaxf(dmx, bmx[(b << 3) + q]);
    }
    const float vMn = sigm(dmn), vMx = sigm(dmx);
    const float vScale = 16.f / ((vMx > vMn) ? (vMx - vMn) : 1.f);
    // conflict-free private hists: hloc[bin*256 + tid] -> bank = tid&31
    __shared__ int hloc[16 * 256];
    __shared__ int part[64];
#pragma unroll
    for (int q = 0; q < 16; ++q) hloc[q * 256 + tid] = 0;
    __syncthreads();
    if (i0 < nn) {
        const int arow = i0 + (lane & 15);
        const int koff = (lane >> 4) * 8;
        bf16x8 a = {0, 0, 0, 0, 0, 0, 0, 0};
        if (arow < c1) a = *(const bf16x8*)(afb + (size_t)(s1 + arow) * 32 + koff);
        const int ibase = i0 + (lane >> 4) * 4;
        const int njt = (nn + 15) >> 4;
        for (int jt = 0; jt < njt; ++jt) {
            const int brow = jt * 16 + (lane & 15);
            bf16x8 bb = {0, 0, 0, 0, 0, 0, 0, 0};
            if (brow < c2) bb = *(const bf16x8*)(afb + (size_t)(s2 + brow) * 32 + koff);
            f32x4 cc = {0.f, 0.f, 0.f, 0.f};
            cc = __builtin_amdgcn_mfma_f32_16x16x32_bf16(a, bb, cc, 0, 0, 0);
            if (brow < nn) {
#pragma unroll
                for (int r = 0; r < 4; ++r) {
                    if (ibase + r < nn) {
                        float t = (sigm(cc[r]) - vMn) * vScale;
                        int bi = (int)floorf(t);
                        bi = bi < 0 ? 0 : (bi > 15 ? 15 : bi);
                        hloc[bi * 256 + tid] += 1;
                    }
                }
            }
        }
    }
    __syncthreads();
    if (tid < 64) {
        const int bin = tid & 15, q = tid >> 4;
        int s = 0;
        for (int t2 = q * 64; t2 < q * 64 + 64; ++t2) s += hloc[bin * 256 + t2];
        part[tid] = s;
    }
    __syncthreads();
    if (tid < 16) {
        int s = part[tid] + part[16 + tid] + part[32 + tid] + part[48 + tid];
        atomicAdd(&hist[b * 16 + tid], (float)s);
    }
}

// ---------------- NTN + final MLP (one block per graph) ----------------
__global__ __launch_bounds__(64) void final_k(const float* __restrict__ pool, const float* __restrict__ hist,
                                              const int* __restrict__ cnt,
                                              const float* __restrict__ ntnW, const float* __restrict__ ntnV,
                                              const float* __restrict__ ntnb, const float* __restrict__ fc1W,
                                              const float* __restrict__ fc1b, const float* __restrict__ scW,
                                              const float* __restrict__ scb, float* __restrict__ out) {
    const int b = blockIdx.x;
    const int tid = threadIdx.x;
    __shared__ float P1[32], P2[32], feat[32], red[64];
    if (tid < 32) { P1[tid] = pool[b * 32 + tid]; P2[tid] = pool[4096 + b * 32 + tid]; }
    __syncthreads();
    const int k = tid & 15, part = tid >> 4;
    float acc = 0.f;
    for (int i = part * 8; i < part * 8 + 8; ++i) {
        float p1i = P1[i];
        for (int j = 0; j < 32; ++j) acc += p1i * P2[j] * ntnW[(i * 32 + j) * 16 + k];
    }
    red[tid] = acc;
    __syncthreads();
    if (tid < 16) {
        float bl = red[tid] + red[16 + tid] + red[32 + tid] + red[48 + tid];
        float blk = ntnb[tid];
        for (int i = 0; i < 32; ++i) blk += P1[i] * ntnV[tid * 64 + i];
        for (int j = 0; j < 32; ++j) blk += P2[j] * ntnV[tid * 64 + 32 + j];
        feat[tid] = fmaxf(bl + blk, 0.f);
        const int nn = max(cnt[b], cnt[128 + b]);
        feat[16 + tid] = hist[b * 16 + tid] / (float)(nn * nn);
    }
    __syncthreads();
    if (tid < 16) {
        float h = fc1b[tid];
        for (int f = 0; f < 32; ++f) h += feat[f] * fc1W[f * 16 + tid];
        red[tid] = fmaxf(h, 0.f);
    }
    __syncthreads();
    if (tid == 0) {
        float o = scb[0];
        for (int j = 0; j < 16; ++j) o += red[j] * scW[j];
        out[b] = 1.f / (1.f + expf(-o));
    }
}

// ---------------- launch ----------------
extern "C" void kernel_launch(void* const* d_in, const int* in_sizes, int n_in,
                              void* d_out, int out_size, void* d_ws, size_t ws_size,
                              hipStream_t stream) {
    const float* x1   = (const float*)d_in[0];
    const float* x2   = (const float*)d_in[1];
    const int*   ei1  = (const int*)d_in[2];
    const int*   ei2  = (const int*)d_in[3];
    const int*   bat1 = (const int*)d_in[4];
    const int*   bat2 = (const int*)d_in[5];
    const float* W1   = (const float*)d_in[6];
    const float* b1   = (const float*)d_in[7];
    const float* W2   = (const float*)d_in[8];
    const float* b2   = (const float*)d_in[9];
    const float* W3   = (const float*)d_in[10];
    const float* b3   = (const float*)d_in[11];
    const float* attW = (const float*)d_in[12];
    const float* ntnW = (const float*)d_in[13];
    const float* ntnV = (const float*)d_in[14];
    const float* ntnb = (const float*)d_in[15];
    const float* fc1W = (const float*)d_in[16];
    const float* fc1b = (const float*)d_in[17];
    const float* scW  = (const float*)d_in[18];
    const float* scb  = (const float*)d_in[19];
    float* out = (float*)d_out;

    // workspace layout (~76 MB)
    ushort16* Hbuf = (ushort16*)d_ws;                    // 131072*64 bf16 (16.8 MB)
    float* Gbuf   = (float*)(Hbuf + (size_t)TOT2 * 64);  // 131072*64 f32  (33.5 MB)
    ushort16* AFb = (ushort16*)(Gbuf + (size_t)TOT2 * 64); // 131072*32 bf16 (8.4 MB)
    float* dis    = (float*)(AFb + (size_t)TOT2 * 32);   // 131072
    int*   deg    = (int*)(dis + TOT2);                  // 131072
    int*   rowptr = deg + TOT2;                          // 131073
    int*   cursor = rowptr + TOT2 + 1;                   // 131072
    int*   csrs   = cursor + TOT2;                       // 2*1048576
    float* csrw   = (float*)(csrs + 2 * (size_t)Ec);     // 2*1048576
    int*   cnt    = (int*)(csrw + 2 * (size_t)Ec);       // 256
    int*   st     = cnt + 256;                           // 256
    float* pool   = (float*)(st + 256);                  // 8192
    float* hist   = pool + 8192;                         // 2048
    float* bmn    = hist + 2048;                         // 1024
    float* bmx    = bmn + 1024;                          // 1024

    hipMemsetAsync(deg, 0, TOT2 * sizeof(int), stream);
    hipMemsetAsync(hist, 0, 2048 * sizeof(float), stream);
    degcnt2_k<<<8192, 256, 0, stream>>>(deg, ei1 + Ec, ei2 + Ec);   // dst = ei[1]
    bs_k<<<1, 256, 0, stream>>>(bat1, bat2, cnt, st);
    dis_k<<<512, 256, 0, stream>>>(dis, deg);
    scan_side_k<<<2, 1024, 0, stream>>>(deg, rowptr, cursor);
    csrfill2_k<<<8192, 256, 0, stream>>>(ei1, ei2, dis, cursor, csrs, csrw);

    // Layer 1 (K=128 -> 64), both sides fused
    gemm_k<128, 64, false><<<512, 256, 0, stream>>>(x1, x2, W1, Hbuf);
    gather_k<64><<<TOT2 / 8, 256, 0, stream>>>(Gbuf, Hbuf, dis, b1, rowptr, csrs, csrw);

    // Layer 2 (64 -> 64), relu fused into GEMM load
    gemm_k<64, 64, true><<<512, 256, 0, stream>>>(Gbuf, Gbuf, W2, Hbuf);
    gather_k<64><<<TOT2 / 8, 256, 0, stream>>>(Gbuf, Hbuf, dis, b2, rowptr, csrs, csrw);

    // Layer 3 (64 -> 32), bf16 AF output
    gemm_k<64, 32, true><<<512, 256, 0, stream>>>(Gbuf, Gbuf, W3, Hbuf);
    gather32b_k<<<TOT2 / 16, 256, 0, stream>>>((uint32*)AFb, Hbuf, dis, b3, rowptr, csrs, csrw);

    // Pooling, histogram, head
    attpool_k<<<256, 256, 0, stream>>>(AFb, cnt, st, attW, pool);
    mm2_k<<<1024, 256, 0, stream>>>(AFb, cnt, st, bmn, bmx);
    bin2_k<<<1024, 256, 0, stream>>>(AFb, cnt, st, bmn, bmx, hist);
    final_k<<<128, 64, 0, stream>>>(pool, hist, cnt, ntnW, ntnV, ntnb, fc1W, fc1b, scW, scb, out);
}